// Round 6
// baseline (808.950 us; speedup 1.0000x reference)
//
#include <hip/hip_runtime.h>
#include <cfloat>
#include <cmath>

#define DEV __device__ __forceinline__

constexpr int BB = 2, NN = 8192, KK = 16, CIN = 32, HH = 32, CO = 64, C2 = 128;
constexpr int BNTOT = BB * NN;        // 16384
constexpr int BNKROWS = BB * NN * KK; // 262144
constexpr float EPSF = 1e-6f;
constexpr int NCELL = 4096;           // 16^3 morton cells
constexpr int NCHUNK = 128;           // 8192/64 chunks per batch

// stats indices (doubles): [sum.., sumsq..] per group
constexpr int S_LSE1 = 0, S_LSE2 = 64, S_ATT1 = 128, S_ATT2 = 192, S_SHORT = 320, S_TOTAL = 576;

// workspace layout (in floats)
constexpr size_t OFF_CP4   = 0;                                  // orig-order (x,y,z,sq): 16384*4
constexpr size_t OFF_SE    = OFF_CP4 + (size_t)BNTOT * 4;        // se (B,N,K,10)
constexpr size_t OFF_XF    = OFF_SE + (size_t)BNKROWS * 10;      // mlp1 out (B,N,32)
constexpr size_t OFF_SHORT = OFF_XF + (size_t)BNTOT * HH;        // shortcut pre-BN (B,N,128)
constexpr size_t OFF_PRE1  = OFF_SHORT + (size_t)BNTOT * C2;     // att1 pre-BN (B,N,32)
constexpr size_t OFF_PRE2  = OFF_PRE1 + (size_t)BNTOT * HH;      // att2 pre-BN (B,N,64)
constexpr size_t OFF_STATS = OFF_PRE2 + (size_t)BNTOT * CO;      // doubles x576
constexpr size_t OFF_COUNTS= OFF_STATS + 2 * S_TOTAL;            // int[2][4096]
// sort scratch overlaid inside the SHORT region (dead until k_feat, which runs after k_knn)
constexpr size_t OFF_CODE  = OFF_SHORT;                          // int[16384]
constexpr size_t OFF_CPS   = OFF_CODE + 16384;                   // float4[2][8192] + 4 pad
constexpr size_t OFF_OIDX  = OFF_CPS + (size_t)BNTOT * 4 + 16;   // int[2][8192]
constexpr size_t OFF_BBOX  = OFF_OIDX + 16384;                   // float[256][8]

DEV unsigned spr3(unsigned v) {
    return (v & 1u) | ((v & 2u) << 2) | ((v & 4u) << 4) | ((v & 8u) << 6);
}

// ---------------- K0: pack (x,y,z,sq) + morton cell + counts ----------------
__global__ __launch_bounds__(256) void k_prep(const float* __restrict__ coords,
                                              float4* __restrict__ cp4,
                                              int* __restrict__ code, int* __restrict__ counts) {
#pragma clang fp contract(off)
    int i = blockIdx.x * 256 + threadIdx.x;
    if (i >= BNTOT) return;
    float x = coords[3 * i], y = coords[3 * i + 1], z = coords[3 * i + 2];
    float sq = (x * x + y * y) + z * z;   // match numpy sum order, no FMA
    cp4[i] = make_float4(x, y, z, sq);
    const float inv = 16.f / 8.8f;
    int ix = min(15, max(0, (int)floorf((x + 4.4f) * inv)));
    int iy = min(15, max(0, (int)floorf((y + 4.4f) * inv)));
    int iz = min(15, max(0, (int)floorf((z + 4.4f) * inv)));
    unsigned m = spr3(ix) | (spr3(iy) << 1) | (spr3(iz) << 2);
    code[i] = (int)m;
    atomicAdd(&counts[((i >> 13) << 12) + m], 1);
}

// ---------------- K0b: exclusive prefix scan of counts (per batch) ----------------
__global__ __launch_bounds__(256) void k_scan(int* __restrict__ counts) {
    __shared__ int lds[256];
    int t = threadIdx.x;
    for (int b = 0; b < 2; ++b) {
        int base = b * NCELL;
        int v[16]; int s = 0;
#pragma unroll
        for (int k = 0; k < 16; ++k) { int tmp = counts[base + t * 16 + k]; v[k] = s; s += tmp; }
        lds[t] = s;
        __syncthreads();
        for (int o = 1; o < 256; o <<= 1) {
            int u = (t >= o) ? lds[t - o] : 0;
            __syncthreads();
            lds[t] += u;
            __syncthreads();
        }
        int off = lds[t] - s;   // exclusive
#pragma unroll
        for (int k = 0; k < 16; ++k) counts[base + t * 16 + k] = off + v[k];
        __syncthreads();
    }
}

// ---------------- K0c: scatter into sorted order ----------------
__global__ __launch_bounds__(256) void k_scatter(const float4* __restrict__ cp4,
                                                 const int* __restrict__ code,
                                                 int* __restrict__ cursor,
                                                 float4* __restrict__ cps, int* __restrict__ oidx) {
    int i = blockIdx.x * 256 + threadIdx.x;
    if (i >= BNTOT) return;
    int b = i >> 13, n = i & 8191;
    int c = code[i];
    int pos = atomicAdd(&cursor[(b << 12) + c], 1);
    cps[(b << 13) + pos] = cp4[i];
    oidx[(b << 13) + pos] = n;
}

// ---------------- K0d: per-chunk bbox ----------------
__global__ __launch_bounds__(64) void k_bbox(const float4* __restrict__ cps,
                                             float* __restrict__ bboxg) {
    int c = blockIdx.x, lane = threadIdx.x;
    float4 p = cps[c * 64 + lane];
    float lox = p.x, hix = p.x, loy = p.y, hiy = p.y, loz = p.z, hiz = p.z;
    for (int o = 32; o > 0; o >>= 1) {
        lox = fminf(lox, __shfl_down(lox, o)); hix = fmaxf(hix, __shfl_down(hix, o));
        loy = fminf(loy, __shfl_down(loy, o)); hiy = fmaxf(hiy, __shfl_down(hiy, o));
        loz = fminf(loz, __shfl_down(loz, o)); hiz = fmaxf(hiz, __shfl_down(hiz, o));
    }
    if (lane == 0) {
        float* bb = bboxg + c * 8;
        bb[0] = lox; bb[1] = loy; bb[2] = loz; bb[3] = hix; bb[4] = hiy; bb[5] = hiz;
    }
}

DEV float dist2(float4 qc, float4 c) {
#pragma clang fp contract(off)
    float dot = (qc.x * c.x + qc.y * c.y) + qc.z * c.z;
    return (qc.w + c.w) - 2.0f * dot;   // exact jax/np expansion formula
}

DEV float md2box(float4 q, const float* bb) {
    float dx = fmaxf(0.f, fmaxf(bb[0] - q.x, q.x - bb[3]));
    float dy = fmaxf(0.f, fmaxf(bb[1] - q.y, q.y - bb[4]));
    float dz = fmaxf(0.f, fmaxf(bb[2] - q.z, q.z - bb[5]));
    return dx * dx + dy * dy + dz * dz;
}

DEV float bb_md2(const float* A, const float* B) {   // box-to-box min dist^2 (lo0..2, hi3..5)
    float dx = fmaxf(0.f, fmaxf(B[0] - A[3], A[0] - B[3]));
    float dy = fmaxf(0.f, fmaxf(B[1] - A[4], A[1] - B[4]));
    float dz = fmaxf(0.f, fmaxf(B[2] - A[5], A[2] - B[5]));
    return dx * dx + dy * dy + dz * dz;
}

// order-preserving float->uint encoding
DEV unsigned encf(float f) {
    unsigned u = __float_as_uint(f);
    return (u & 0x80000000u) ? ~u : (u | 0x80000000u);
}
DEV float decf(unsigned e) {
    unsigned u = (e & 0x80000000u) ? (e & 0x7FFFFFFFu) : ~e;
    return __uint_as_float(u);
}

// lexicographic (d, orig-idx) sorted insert
DEV void ins16_lex(float (&dl)[16], int (&il)[16], float d, int id) {
    float dk = d; int jk = id;
#pragma unroll
    for (int r = 0; r < 16; ++r) {
        bool c = (dk < dl[r]) || (dk == dl[r] && jk < il[r]);
        float td = dl[r]; int ti = il[r];
        dl[r] = c ? dk : dl[r]; il[r] = c ? jk : il[r];
        dk = c ? td : dk; jk = c ? ti : jk;
    }
}

// ---------------- K1: balanced chunk-queue KNN + spatial encoding ----------------
// grid 512 = 2 batches x 256 groups of 32 sorted queries; block 256.
// All 128 chunks ranked nearest-first vs the GROUP query bbox (box-to-box md2);
// round r: partition p scans chunk sorted[8r+p] -> all 8 waves busy on the 8
// nearest unprocessed chunks. Uniform stop when the next-nearest chunk cannot
// beat any query's (conservative) threshold. Same exact-selection semantics.
__global__ __launch_bounds__(256) void k_knn(const float4* __restrict__ cps,
                                             const int* __restrict__ oidx,
                                             const float4* __restrict__ cp4,
                                             const float* __restrict__ bboxg,
                                             float* __restrict__ se) {
    __shared__ __align__(16) float mdl[8][32][17];
    __shared__ int   mil[8][32][17];
    __shared__ float bbx[128][8];
    __shared__ float cmd[128];
    __shared__ float smd[128];
    __shared__ int   order_s[128];
    __shared__ unsigned thr[32];
    __shared__ float gbox[6];
    __shared__ int   stop_s;
    uint2 (*buf)[256] = reinterpret_cast<uint2(*)[256]>(&mdl[0][0][0]);  // overlay, 14336B < 17408B

    int t = threadIdx.x;
    int b = blockIdx.x >> 8;
    int qbase = (blockIdx.x & 255) * 32;
    int ql = t & 31, part = t >> 5;
    const float4* cb_ = cps + ((size_t)b << 13);
    const int* ob_ = oidx + (b << 13);
    float4 qc = cb_[qbase + ql];

    for (int e = t; e < 1024; e += 256) ((float*)bbx)[e] = bboxg[(b << 10) + e];
    if (t < 32) thr[t] = encf(FLT_MAX);
    if (t < 64) {   // group bbox (lanes 32-63 duplicate queries -> full-wave reduce ok)
        float lox = qc.x, hix = qc.x, loy = qc.y, hiy = qc.y, loz = qc.z, hiz = qc.z;
        for (int o = 32; o > 0; o >>= 1) {
            lox = fminf(lox, __shfl_down(lox, o)); hix = fmaxf(hix, __shfl_down(hix, o));
            loy = fminf(loy, __shfl_down(loy, o)); hiy = fmaxf(hiy, __shfl_down(hiy, o));
            loz = fminf(loz, __shfl_down(loz, o)); hiz = fmaxf(hiz, __shfl_down(hiz, o));
        }
        if (t == 0) { gbox[0] = lox; gbox[1] = loy; gbox[2] = loz; gbox[3] = hix; gbox[4] = hiy; gbox[5] = hiz; }
    }
    __syncthreads();

    if (t < 128) cmd[t] = bb_md2(gbox, &bbx[t][0]);
    __syncthreads();
    if (t < 128) {   // rank sort (stable by chunk idx)
        float v = cmd[t]; int rank = 0;
        for (int j = 0; j < 128; ++j) {
            float u = cmd[j];
            rank += (u < v) || (u == v && j < t);
        }
        order_s[rank] = t; smd[rank] = v;
    }
    __syncthreads();

    float dl[16]; int il[16];
#pragma unroll
    for (int i = 0; i < 16; ++i) { dl[i] = FLT_MAX; il[i] = 0x7fffffff; }

    // seed: first 16 candidates of partition's round-0 chunk
    int cseed = order_s[part];
    {
        int j0 = cseed * 64;
#pragma unroll
        for (int k = 0; k < 16; ++k) {
            float d = dist2(qc, cb_[j0 + k]);
            int o = ob_[j0 + k];
            if (d < dl[15] || (d == dl[15] && o < il[15])) ins16_lex(dl, il, d, o);
        }
    }
    atomicMin(&thr[ql], encf(dl[15]));
    float Tf = dl[15];
    unsigned te = thr[ql];
    int cnt = 0;

    for (int r = 0; r < 16; ++r) {
        int c = order_s[8 * r + part];
        float md2v = md2box(qc, &bbx[c][0]);
        bool need = md2v <= Tf * 1.001f + 1e-3f;   // conservative (covers expansion-formula fp error)
        if (__any(need)) {
            int jb = c * 64 + (r == 0 ? 16 : 0);
            int je = c * 64 + 64;
            float4 n0 = cb_[jb], n1 = cb_[jb + 1], n2 = cb_[jb + 2], n3 = cb_[jb + 3];
            for (int j = jb; j < je; j += 4) {
                float4 c0_ = n0, c1_ = n1, c2_ = n2, c3_ = n3;
                n0 = cb_[j + 4]; n1 = cb_[j + 5]; n2 = cb_[j + 6]; n3 = cb_[j + 7]; // tail over-read stays in padded ws
                float d0 = dist2(qc, c0_), d1 = dist2(qc, c1_), d2v = dist2(qc, c2_), d3 = dist2(qc, c3_);
                bool p0 = d0 <= Tf, p1 = d1 <= Tf, p2 = d2v <= Tf, p3 = d3 <= Tf;
                if (__any(p0 | p1 | p2 | p3)) {
                    if (p0) { buf[cnt][t] = make_uint2(__float_as_uint(d0), (unsigned)j); ++cnt; }
                    if (p1) { buf[cnt][t] = make_uint2(__float_as_uint(d1), (unsigned)(j + 1)); ++cnt; }
                    if (p2) { buf[cnt][t] = make_uint2(__float_as_uint(d2v), (unsigned)(j + 2)); ++cnt; }
                    if (p3) { buf[cnt][t] = make_uint2(__float_as_uint(d3), (unsigned)(j + 3)); ++cnt; }
                    if (__any(cnt >= 4)) {
                        unsigned jj[7]; int oid[7];
#pragma unroll
                        for (int q2 = 0; q2 < 7; ++q2) jj[q2] = (q2 < cnt) ? buf[q2][t].y : 0u;
#pragma unroll
                        for (int q2 = 0; q2 < 7; ++q2) oid[q2] = ob_[jj[q2]];
#pragma unroll
                        for (int q2 = 0; q2 < 7; ++q2) {
                            if (q2 < cnt) {
                                float d = __uint_as_float(buf[q2][t].x); int o = oid[q2];
                                if (d < dl[15] || (d == dl[15] && o < il[15])) ins16_lex(dl, il, d, o);
                            }
                        }
                        cnt = 0;
                        atomicMin(&thr[ql], encf(dl[15]));
                    }
                }
                Tf = fminf(Tf, decf(te));
                te = thr[ql];
            }
        }
        atomicMin(&thr[ql], encf(dl[15]));
        __syncthreads();
        if (t == 0) {
            float mt = 0.f;
            for (int i = 0; i < 32; ++i) mt = fmaxf(mt, decf(thr[i]));
            stop_s = (r == 15) || (smd[8 * (r + 1)] > mt * 1.001f + 1e-3f);
        }
        __syncthreads();
        if (stop_s) break;
        Tf = fminf(Tf, decf(thr[ql]));
        te = thr[ql];
    }
    if (__any(cnt > 0)) {   // final flush
        unsigned jj[7]; int oid[7];
#pragma unroll
        for (int q2 = 0; q2 < 7; ++q2) jj[q2] = (q2 < cnt) ? buf[q2][t].y : 0u;
#pragma unroll
        for (int q2 = 0; q2 < 7; ++q2) oid[q2] = ob_[jj[q2]];
#pragma unroll
        for (int q2 = 0; q2 < 7; ++q2) {
            if (q2 < cnt) {
                float d = __uint_as_float(buf[q2][t].x); int o = oid[q2];
                if (d < dl[15] || (d == dl[15] && o < il[15])) ins16_lex(dl, il, d, o);
            }
        }
    }

    __syncthreads();   // protect buf -> mdl overlay
#pragma unroll
    for (int i = 0; i < 16; ++i) { mdl[part][ql][i] = dl[i]; mil[part][ql][i] = il[i]; }
    mdl[part][ql][16] = FLT_MAX; mil[part][ql][16] = 0x7fffffff;  // merge sentinel
    __syncthreads();

    // 8-way streaming merge: one thread per query picks lex-min 16 times
    if (t < 32) {
        int hp[8]; float hd[8]; int hi_[8];
#pragma unroll
        for (int p = 0; p < 8; ++p) { hp[p] = 0; hd[p] = mdl[p][t][0]; hi_[p] = mil[p][t][0]; }
        float od[16]; int oi[16];
#pragma unroll
        for (int s = 0; s < 16; ++s) {
            float bd = hd[0]; int bi_ = hi_[0]; int bp = 0;
#pragma unroll
            for (int p = 1; p < 8; ++p) {
                bool cc = (hd[p] < bd) || (hd[p] == bd && hi_[p] < bi_);
                bd = cc ? hd[p] : bd; bi_ = cc ? hi_[p] : bi_; bp = cc ? p : bp;
            }
            od[s] = bd; oi[s] = bi_;
#pragma unroll
            for (int p = 0; p < 8; ++p) {
                if (p == bp) { ++hp[p]; hd[p] = mdl[p][t][hp[p]]; hi_[p] = mil[p][t][hp[p]]; }
            }
        }
#pragma unroll
        for (int s = 0; s < 16; ++s) { mdl[0][t][s] = od[s]; mil[0][t][s] = oi[s]; }
    }
    __syncthreads();

    // epilogue: write se rows (scatter to original query index)
    for (int s2 = t; s2 < 512; s2 += 256) {
        int qq = s2 >> 4, k = s2 & 15;
        float d2s = mdl[0][qq][k]; int oid = mil[0][qq][k];
        float4 qc2 = cb_[qbase + qq];
        int oq = ob_[qbase + qq];
        float4 nb = cp4[(b << 13) + oid];
        float dist = sqrtf(fmaxf(d2s, 1e-12f));
        float* sp = se + ((size_t)(b * NN + oq) * KK + k) * 10;
        sp[0] = qc2.x; sp[1] = qc2.y; sp[2] = qc2.z;
        sp[3] = nb.x;  sp[4] = nb.y;  sp[5] = nb.z;
        sp[6] = qc2.x - nb.x; sp[7] = qc2.y - nb.y; sp[8] = qc2.z - nb.z;
        sp[9] = dist;
    }
}

// ---------------- K2: mlp1 + shortcut linear + shortcut BN stats ----------------
__global__ __launch_bounds__(128) void k_feat(const float* __restrict__ feat,
                                              const float* __restrict__ Wm1, const float* __restrict__ bm1,
                                              const float* __restrict__ Wsh, const float* __restrict__ bsh,
                                              float* __restrict__ xf, float* __restrict__ short_pre,
                                              double* __restrict__ stats) {
    __shared__ float fl[32][33];
    int t = threadIdx.x;
    int pbase = blockIdx.x * 32;
    float wcol[32];
#pragma unroll
    for (int i = 0; i < 32; ++i) wcol[i] = Wsh[i * C2 + t];
    float wm[32];
    if (t < 32) {
#pragma unroll
        for (int i = 0; i < 32; ++i) wm[i] = Wm1[i * HH + t];
    }
    float bs = bsh[t];
    float bm = (t < 32) ? bm1[t] : 0.f;
    double s = 0.0, s2 = 0.0;

    for (int e = t; e < 1024; e += 128) {
        int p = e >> 5, i = e & 31;
        fl[p][i] = feat[(size_t)(pbase + p) * CIN + i];
    }
    __syncthreads();
    for (int p = 0; p < 32; ++p) {
        float acc = bs;
#pragma unroll
        for (int i = 0; i < 32; ++i) acc += fl[p][i] * wcol[i];
        int gp = pbase + p;
        short_pre[(size_t)gp * C2 + t] = acc;
        s += acc; s2 += (double)acc * acc;
        if (t < 32) {
            float xv = bm;
#pragma unroll
            for (int i = 0; i < 32; ++i) xv += fl[p][i] * wm[i];
            xf[(size_t)gp * HH + t] = xv >= 0.f ? xv : 0.2f * xv;
        }
    }
    atomicAdd(&stats[S_SHORT + t], s);
    atomicAdd(&stats[S_SHORT + C2 + t], s2);
}

// ---------------- K3: lse1+lse2 linear BN stats (LDS-staged) ----------------
__global__ __launch_bounds__(256) void k_lse_stats(const float* __restrict__ se,
                                                   const float* __restrict__ W1, const float* __restrict__ b1,
                                                   const float* __restrict__ W2, const float* __restrict__ b2,
                                                   double* __restrict__ stats) {
    __shared__ float srows[256][10];
    __shared__ double red[4][64][2];
    int t = threadIdx.x;
    int c = t & 63, grp = t >> 6;
    int ch = c & 31; bool second = c >= 32;
    const float* W = second ? W2 : W1;
    float wcol[10];
#pragma unroll
    for (int d = 0; d < 10; ++d) wcol[d] = W[d * HH + ch];
    float bb = second ? b2[ch] : b1[ch];
    double s = 0.0, s2 = 0.0;
    int rbase = blockIdx.x * 512;

    for (int tile = 0; tile < 2; ++tile) {
        __syncthreads();
        const float* src = se + (size_t)(rbase + tile * 256) * 10;
        for (int e = t; e < 2560; e += 256) srows[e / 10][e % 10] = src[e];
        __syncthreads();
        int r0 = grp * 64;
        for (int r = r0; r < r0 + 64; ++r) {
            float acc = bb;
#pragma unroll
            for (int d = 0; d < 10; ++d) acc += srows[r][d] * wcol[d];
            s += acc; s2 += (double)acc * acc;
        }
    }
    red[grp][c][0] = s; red[grp][c][1] = s2;
    __syncthreads();
    if (grp == 0) {
        for (int g = 1; g < 4; ++g) { s += red[g][c][0]; s2 += red[g][c][1]; }
        int base = second ? S_LSE2 : S_LSE1;
        atomicAdd(&stats[base + ch], s);
        atomicAdd(&stats[base + 32 + ch], s2);
    }
}

// BN scale/shift from raw stats (computed redundantly in consumer prologues)
DEV float2 fin_pair(const double* stats, int sbase, int ch, int nch, double M,
                    const float* g, const float* be) {
    double mean = stats[sbase + ch] / M;
    double var = stats[sbase + nch + ch] / M - mean * mean;
    double scd = (double)g[ch] / sqrt(var + (double)EPSF);
    return make_float2((float)scd, (float)((double)be[ch] - mean * scd));
}

// ---------------- K5/K7: fused LocSE + attentive pooling + MLP ----------------
template <int OUTC, bool SECOND>
__global__ __launch_bounds__(256) void k_att(const float* __restrict__ se,
                                             const float* __restrict__ featsrc,
                                             const float* __restrict__ Wlse, const float* __restrict__ blse,
                                             const float* __restrict__ Wlin,
                                             const float* __restrict__ Wmlp, const float* __restrict__ bmlp,
                                             double* __restrict__ stats, int lse_sbase, int feat_sbase, int stat_base,
                                             const float* __restrict__ g_lse, const float* __restrict__ be_lse,
                                             const float* __restrict__ g_f, const float* __restrict__ be_f,
                                             float* __restrict__ preout) {
    __shared__ __align__(16) float wlt[64][68];
    __shared__ float wm[64][OUTC];
    __shared__ __align__(16) float x1[4][16][40];
    __shared__ float fv[4][32];
    __shared__ float p1b[4][64];
    __shared__ double red[4][OUTC][2];

    int t = threadIdx.x, w = t >> 6, c = t & 63;
    int ch = c & 31, half = c >> 5;
    for (int e = t; e < 4096; e += 256) wlt[e & 63][e >> 6] = Wlin[e];
    for (int e = t; e < 64 * OUTC; e += 256) wm[e / OUTC][e % OUTC] = Wmlp[e];

    float wf[10]; float bf;
    {
        float2 p = fin_pair(stats, lse_sbase, ch, 32, (double)BNKROWS, g_lse, be_lse);
#pragma unroll
        for (int d = 0; d < 10; ++d) wf[d] = Wlse[d * 32 + ch] * p.x;
        bf = blse[ch] * p.x + p.y;
    }
    float fa = 1.f, fb = 0.f;
    if (SECOND && c >= 32) {
        float2 p = fin_pair(stats, feat_sbase, ch, 32, (double)BNTOT, g_f, be_f);
        fa = p.x; fb = p.y;
    }
    double s = 0.0, s2 = 0.0;
    __syncthreads();

    for (int i = 0; i < 8; ++i) {
        int p = blockIdx.x * 32 + w * 8 + i;

        int kbase = half * 8;
        const float* sp = se + (size_t)p * (KK * 10) + kbase * 10;
        float myv[8];
#pragma unroll
        for (int kk = 0; kk < 8; ++kk) {
            float acc = bf;
#pragma unroll
            for (int d = 0; d < 10; ++d) acc += sp[kk * 10 + d] * wf[d];
            myv[kk] = fmaxf(acc, 0.f);
        }
#pragma unroll
        for (int kk = 0; kk < 8; ++kk) x1[w][kbase + kk][ch] = myv[kk];

        float xv = 0.f;
        if (c >= 32) {
            xv = featsrc[(size_t)p * 32 + ch];
            if (SECOND) xv = fmaxf(xv * fa + fb, 0.f);
            fv[w][ch] = xv;
        }

        float col[16];
        if (c < 32) {
#pragma unroll
            for (int kk = 0; kk < 8; ++kk) col[kk] = myv[kk];
#pragma unroll
            for (int kk = 0; kk < 8; ++kk) col[8 + kk] = x1[w][8 + kk][ch];
        } else {
#pragma unroll
            for (int k = 0; k < 16; ++k) col[k] = xv;
        }

        float cst = 0.f;
#pragma unroll
        for (int dg = 8; dg < 16; ++dg) {
            float4 wv = *(const float4*)&wlt[c][dg * 4];
            float4 xvv = *(const float4*)&fv[w][(dg - 8) * 4];
            cst += xvv.x * wv.x + xvv.y * wv.y + xvv.z * wv.z + xvv.w * wv.w;
        }
        float scv[16];
#pragma unroll
        for (int k = 0; k < 16; ++k) scv[k] = cst;
        for (int dg = 0; dg < 8; ++dg) {
            float4 wv = *(const float4*)&wlt[c][dg * 4];
#pragma unroll
            for (int k = 0; k < 16; ++k) {
                float4 xvv = *(const float4*)&x1[w][k][dg * 4];
                scv[k] += xvv.x * wv.x + xvv.y * wv.y + xvv.z * wv.z + xvv.w * wv.w;
            }
        }
        float m = scv[0];
#pragma unroll
        for (int k = 1; k < 16; ++k) m = fmaxf(m, scv[k]);
        float sum = 0.f, p1 = 0.f;
#pragma unroll
        for (int k = 0; k < 16; ++k) { float e = __expf(scv[k] - m); sum += e; p1 += e * col[k]; }
        p1 /= sum;
        p1b[w][c] = p1;

        if (c < OUTC) {
            float acc = bmlp[c];
#pragma unroll
            for (int d = 0; d < 64; ++d) acc += p1b[w][d] * wm[d][c];
            preout[(size_t)p * OUTC + c] = acc;
            s += acc; s2 += (double)acc * acc;
        }
    }
    if (c < OUTC) { red[w][c][0] = s; red[w][c][1] = s2; }
    __syncthreads();
    if (t < OUTC) {
        double ts = red[0][t][0], ts2 = red[0][t][1];
        for (int g = 1; g < 4; ++g) { ts += red[g][t][0]; ts2 += red[g][t][1]; }
        atomicAdd(&stats[stat_base + t], ts);
        atomicAdd(&stats[stat_base + OUTC + t], ts2);
    }
}

// ---------------- K9: final mlp2 + shortcut BN + residual leaky + transposed write ----
__global__ __launch_bounds__(256) void k_out(const float* __restrict__ pre2,
                                             const float* __restrict__ short_pre,
                                             const float* __restrict__ W2, const float* __restrict__ b2,
                                             const double* __restrict__ stats,
                                             const float* __restrict__ g_a2, const float* __restrict__ be_a2,
                                             const float* __restrict__ g_s, const float* __restrict__ be_s,
                                             float* __restrict__ out) {
    __shared__ __align__(16) float w2[64][128];
    __shared__ float sc2[64], sh2[64], scs[128], shs[128], bb[128];
    int t = threadIdx.x;
    int pl = t & 63, seg = t >> 6;
    for (int e = t; e < 8192; e += 256) w2[e >> 7][e & 127] = W2[e];
    if (t < 64) { float2 p = fin_pair(stats, S_ATT2, t, 64, (double)BNTOT, g_a2, be_a2); sc2[t] = p.x; sh2[t] = p.y; }
    if (t >= 64 && t < 192) { int ch = t - 64; float2 p = fin_pair(stats, S_SHORT, ch, 128, (double)BNTOT, g_s, be_s); scs[ch] = p.x; shs[ch] = p.y; }
    if (t < 128) bb[t] = b2[t];
    __syncthreads();

    int p = blockIdx.x * 64 + pl;
    int b = p >> 13, n = p & 8191;
    const float* pr = pre2 + (size_t)p * 64;
    float xa[64];
#pragma unroll
    for (int c = 0; c < 64; c += 4) {
        float4 v = *(const float4*)&pr[c];
        xa[c + 0] = fmaxf(v.x * sc2[c + 0] + sh2[c + 0], 0.f);
        xa[c + 1] = fmaxf(v.y * sc2[c + 1] + sh2[c + 1], 0.f);
        xa[c + 2] = fmaxf(v.z * sc2[c + 2] + sh2[c + 2], 0.f);
        xa[c + 3] = fmaxf(v.w * sc2[c + 3] + sh2[c + 3], 0.f);
    }
    const float* shp = short_pre + (size_t)p * 128;
    int obase = seg * 32;
    for (int o = obase; o < obase + 32; o += 4) {
        float a0 = bb[o], a1 = bb[o + 1], a2 = bb[o + 2], a3 = bb[o + 3];
#pragma unroll
        for (int cc = 0; cc < 64; ++cc) {
            float4 wv = *(const float4*)&w2[cc][o];
            float x = xa[cc];
            a0 += x * wv.x; a1 += x * wv.y; a2 += x * wv.z; a3 += x * wv.w;
        }
        float4 sv = *(const float4*)&shp[o];
        float r0 = a0 + (sv.x * scs[o] + shs[o]);
        float r1 = a1 + (sv.y * scs[o + 1] + shs[o + 1]);
        float r2 = a2 + (sv.z * scs[o + 2] + shs[o + 2]);
        float r3 = a3 + (sv.w * scs[o + 3] + shs[o + 3]);
        out[((size_t)(b * C2 + o + 0)) * NN + n] = r0 >= 0.f ? r0 : 0.01f * r0;
        out[((size_t)(b * C2 + o + 1)) * NN + n] = r1 >= 0.f ? r1 : 0.01f * r1;
        out[((size_t)(b * C2 + o + 2)) * NN + n] = r2 >= 0.f ? r2 : 0.01f * r2;
        out[((size_t)(b * C2 + o + 3)) * NN + n] = r3 >= 0.f ? r3 : 0.01f * r3;
    }
}

extern "C" void kernel_launch(void* const* d_in, const int* in_sizes, int n_in,
                              void* d_out, int out_size, void* d_ws, size_t ws_size,
                              hipStream_t stream) {
    const float* coords    = (const float*)d_in[0];
    const float* features  = (const float*)d_in[1];
    const float* W_mlp1    = (const float*)d_in[2];
    const float* b_mlp1    = (const float*)d_in[3];
    const float* W_lse1    = (const float*)d_in[4];
    const float* b_lse1    = (const float*)d_in[5];
    const float* g_lse1    = (const float*)d_in[6];
    const float* be_lse1   = (const float*)d_in[7];
    const float* W_att1_lin= (const float*)d_in[8];
    const float* W_att1_mlp= (const float*)d_in[9];
    const float* b_att1_mlp= (const float*)d_in[10];
    const float* g_att1    = (const float*)d_in[11];
    const float* be_att1   = (const float*)d_in[12];
    const float* W_lse2    = (const float*)d_in[13];
    const float* b_lse2    = (const float*)d_in[14];
    const float* g_lse2    = (const float*)d_in[15];
    const float* be_lse2   = (const float*)d_in[16];
    const float* W_att2_lin= (const float*)d_in[17];
    const float* W_att2_mlp= (const float*)d_in[18];
    const float* b_att2_mlp= (const float*)d_in[19];
    const float* g_att2    = (const float*)d_in[20];
    const float* be_att2   = (const float*)d_in[21];
    const float* W_mlp2    = (const float*)d_in[22];
    const float* b_mlp2    = (const float*)d_in[23];
    const float* W_short   = (const float*)d_in[24];
    const float* b_short   = (const float*)d_in[25];
    const float* g_short   = (const float*)d_in[26];
    const float* be_short  = (const float*)d_in[27];

    float* ws = (float*)d_ws;
    float4* cp4      = (float4*)(ws + OFF_CP4);
    float* se        = ws + OFF_SE;
    float* xf        = ws + OFF_XF;
    float* short_pre = ws + OFF_SHORT;
    float* pre1      = ws + OFF_PRE1;
    float* pre2      = ws + OFF_PRE2;
    double* stats    = (double*)(ws + OFF_STATS);
    int* counts      = (int*)(ws + OFF_COUNTS);
    int* code        = (int*)(ws + OFF_CODE);
    float4* cps      = (float4*)(ws + OFF_CPS);
    int* oidxArr     = (int*)(ws + OFF_OIDX);
    float* bboxg     = ws + OFF_BBOX;
    float* out       = (float*)d_out;

    hipMemsetAsync(stats, 0, S_TOTAL * 8 + 2 * NCELL * 4, stream);

    k_prep<<<BNTOT / 256, 256, 0, stream>>>(coords, cp4, code, counts);
    k_scan<<<1, 256, 0, stream>>>(counts);
    k_scatter<<<BNTOT / 256, 256, 0, stream>>>(cp4, code, counts, cps, oidxArr);
    k_bbox<<<BB * NCHUNK, 64, 0, stream>>>(cps, bboxg);
    k_knn<<<512, 256, 0, stream>>>(cps, oidxArr, cp4, bboxg, se);
    k_feat<<<512, 128, 0, stream>>>(features, W_mlp1, b_mlp1, W_short, b_short,
                                    xf, short_pre, stats);
    k_lse_stats<<<512, 256, 0, stream>>>(se, W_lse1, b_lse1, W_lse2, b_lse2, stats);
    k_att<32, false><<<512, 256, 0, stream>>>(se, xf, W_lse1, b_lse1, W_att1_lin,
                                              W_att1_mlp, b_att1_mlp, stats,
                                              S_LSE1, 0, S_ATT1,
                                              g_lse1, be_lse1, nullptr, nullptr, pre1);
    k_att<64, true><<<512, 256, 0, stream>>>(se, pre1, W_lse2, b_lse2, W_att2_lin,
                                             W_att2_mlp, b_att2_mlp, stats,
                                             S_LSE2, S_ATT1, S_ATT2,
                                             g_lse2, be_lse2, g_att1, be_att1, pre2);
    k_out<<<BNTOT / 64, 256, 0, stream>>>(pre2, short_pre, W_mlp2, b_mlp2, stats,
                                          g_att2, be_att2, g_short, be_short, out);
}

// Round 7
// 796.169 us; speedup vs baseline: 1.0161x; 1.0161x over previous
//
#include <hip/hip_runtime.h>
#include <cfloat>
#include <cmath>

#define DEV __device__ __forceinline__

constexpr int BB = 2, NN = 8192, KK = 16, CIN = 32, HH = 32, CO = 64, C2 = 128;
constexpr int BNTOT = BB * NN;        // 16384
constexpr int BNKROWS = BB * NN * KK; // 262144
constexpr float EPSF = 1e-6f;
constexpr int NCELL = 4096;           // 16^3 morton cells
constexpr int NCHUNK = 128;           // 8192/64 chunks per batch

// stats indices (doubles): [sum.., sumsq..] per group
constexpr int S_LSE1 = 0, S_LSE2 = 64, S_ATT1 = 128, S_ATT2 = 192, S_SHORT = 320, S_TOTAL = 576;

// workspace layout (in floats)
constexpr size_t OFF_CP4   = 0;                                  // orig-order (x,y,z,sq): 16384*4
constexpr size_t OFF_SE    = OFF_CP4 + (size_t)BNTOT * 4;        // se (B,N,K,10)
constexpr size_t OFF_XF    = OFF_SE + (size_t)BNKROWS * 10;      // mlp1 out (B,N,32)
constexpr size_t OFF_SHORT = OFF_XF + (size_t)BNTOT * HH;        // shortcut pre-BN (B,N,128)
constexpr size_t OFF_PRE1  = OFF_SHORT + (size_t)BNTOT * C2;     // att1 pre-BN (B,N,32)
constexpr size_t OFF_PRE2  = OFF_PRE1 + (size_t)BNTOT * HH;      // att2 pre-BN (B,N,64)
constexpr size_t OFF_STATS = OFF_PRE2 + (size_t)BNTOT * CO;      // doubles x576
constexpr size_t OFF_COUNTS= OFF_STATS + 2 * S_TOTAL;            // int[2][4096]
// sort scratch overlaid inside the SHORT region (dead until k_feat, which runs after k_knn)
constexpr size_t OFF_CODE  = OFF_SHORT;                          // int[16384]
constexpr size_t OFF_CPS   = OFF_CODE + 16384;                   // float4[2][8192] + 4 pad
constexpr size_t OFF_OIDX  = OFF_CPS + (size_t)BNTOT * 4 + 16;   // int[2][8192]
constexpr size_t OFF_BBOX  = OFF_OIDX + 16384;                   // float[256][8]

DEV unsigned spr3(unsigned v) {
    return (v & 1u) | ((v & 2u) << 2) | ((v & 4u) << 4) | ((v & 8u) << 6);
}

// ---------------- K0: pack (x,y,z,sq) + morton cell + counts ----------------
__global__ __launch_bounds__(256) void k_prep(const float* __restrict__ coords,
                                              float4* __restrict__ cp4,
                                              int* __restrict__ code, int* __restrict__ counts) {
#pragma clang fp contract(off)
    int i = blockIdx.x * 256 + threadIdx.x;
    if (i >= BNTOT) return;
    float x = coords[3 * i], y = coords[3 * i + 1], z = coords[3 * i + 2];
    float sq = (x * x + y * y) + z * z;   // match numpy sum order, no FMA
    cp4[i] = make_float4(x, y, z, sq);
    const float inv = 16.f / 8.8f;
    int ix = min(15, max(0, (int)floorf((x + 4.4f) * inv)));
    int iy = min(15, max(0, (int)floorf((y + 4.4f) * inv)));
    int iz = min(15, max(0, (int)floorf((z + 4.4f) * inv)));
    unsigned m = spr3(ix) | (spr3(iy) << 1) | (spr3(iz) << 2);
    code[i] = (int)m;
    atomicAdd(&counts[((i >> 13) << 12) + m], 1);
}

// ---------------- K0b: exclusive prefix scan of counts (per batch) ----------------
__global__ __launch_bounds__(256) void k_scan(int* __restrict__ counts) {
    __shared__ int lds[256];
    int t = threadIdx.x;
    for (int b = 0; b < 2; ++b) {
        int base = b * NCELL;
        int v[16]; int s = 0;
#pragma unroll
        for (int k = 0; k < 16; ++k) { int tmp = counts[base + t * 16 + k]; v[k] = s; s += tmp; }
        lds[t] = s;
        __syncthreads();
        for (int o = 1; o < 256; o <<= 1) {
            int u = (t >= o) ? lds[t - o] : 0;
            __syncthreads();
            lds[t] += u;
            __syncthreads();
        }
        int off = lds[t] - s;   // exclusive
#pragma unroll
        for (int k = 0; k < 16; ++k) counts[base + t * 16 + k] = off + v[k];
        __syncthreads();
    }
}

// ---------------- K0c: scatter into sorted order ----------------
__global__ __launch_bounds__(256) void k_scatter(const float4* __restrict__ cp4,
                                                 const int* __restrict__ code,
                                                 int* __restrict__ cursor,
                                                 float4* __restrict__ cps, int* __restrict__ oidx) {
    int i = blockIdx.x * 256 + threadIdx.x;
    if (i >= BNTOT) return;
    int b = i >> 13, n = i & 8191;
    int c = code[i];
    int pos = atomicAdd(&cursor[(b << 12) + c], 1);
    cps[(b << 13) + pos] = cp4[i];
    oidx[(b << 13) + pos] = n;
}

// ---------------- K0d: per-chunk bbox ----------------
__global__ __launch_bounds__(64) void k_bbox(const float4* __restrict__ cps,
                                             float* __restrict__ bboxg) {
    int c = blockIdx.x, lane = threadIdx.x;
    float4 p = cps[c * 64 + lane];
    float lox = p.x, hix = p.x, loy = p.y, hiy = p.y, loz = p.z, hiz = p.z;
    for (int o = 32; o > 0; o >>= 1) {
        lox = fminf(lox, __shfl_down(lox, o)); hix = fmaxf(hix, __shfl_down(hix, o));
        loy = fminf(loy, __shfl_down(loy, o)); hiy = fmaxf(hiy, __shfl_down(hiy, o));
        loz = fminf(loz, __shfl_down(loz, o)); hiz = fmaxf(hiz, __shfl_down(hiz, o));
    }
    if (lane == 0) {
        float* bb = bboxg + c * 8;
        bb[0] = lox; bb[1] = loy; bb[2] = loz; bb[3] = hix; bb[4] = hiy; bb[5] = hiz;
    }
}

DEV float dist2(float4 qc, float4 c) {
#pragma clang fp contract(off)
    float dot = (qc.x * c.x + qc.y * c.y) + qc.z * c.z;
    return (qc.w + c.w) - 2.0f * dot;   // exact jax/np expansion formula
}

DEV float md2box(float4 q, const float* bb) {
    float dx = fmaxf(0.f, fmaxf(bb[0] - q.x, q.x - bb[3]));
    float dy = fmaxf(0.f, fmaxf(bb[1] - q.y, q.y - bb[4]));
    float dz = fmaxf(0.f, fmaxf(bb[2] - q.z, q.z - bb[5]));
    return dx * dx + dy * dy + dz * dz;
}

DEV float bb_md2(const float* A, const float* B) {   // box-to-box min dist^2 (lo0..2, hi3..5)
    float dx = fmaxf(0.f, fmaxf(B[0] - A[3], A[0] - B[3]));
    float dy = fmaxf(0.f, fmaxf(B[1] - A[4], A[1] - B[4]));
    float dz = fmaxf(0.f, fmaxf(B[2] - A[5], A[2] - B[5]));
    return dx * dx + dy * dy + dz * dz;
}

// order-preserving float->uint encoding
DEV unsigned encf(float f) {
    unsigned u = __float_as_uint(f);
    return (u & 0x80000000u) ? ~u : (u | 0x80000000u);
}
DEV float decf(unsigned e) {
    unsigned u = (e & 0x80000000u) ? (e & 0x7FFFFFFFu) : ~e;
    return __uint_as_float(u);
}

// lexicographic (d, orig-idx) sorted insert
DEV void ins16_lex(float (&dl)[16], int (&il)[16], float d, int id) {
    float dk = d; int jk = id;
#pragma unroll
    for (int r = 0; r < 16; ++r) {
        bool c = (dk < dl[r]) || (dk == dl[r] && jk < il[r]);
        float td = dl[r]; int ti = il[r];
        dl[r] = c ? dk : dl[r]; il[r] = c ? jk : il[r];
        dk = c ? td : dk; jk = c ? ti : jk;
    }
}

// ---------------- K1: balanced chunk-queue KNN + spatial encoding ----------------
// grid 512 = 2 batches x 256 groups of 32 sorted queries; block 256.
// All 128 chunks ranked nearest-first vs the GROUP query bbox (box-to-box md2);
// round r: partition p scans chunk sorted[8r+p] -> all 8 waves busy on the 8
// nearest unprocessed chunks. Uniform stop when the next-nearest chunk cannot
// beat any query's (conservative) threshold. Same exact-selection semantics.
__global__ __launch_bounds__(256) void k_knn(const float4* __restrict__ cps,
                                             const int* __restrict__ oidx,
                                             const float4* __restrict__ cp4,
                                             const float* __restrict__ bboxg,
                                             float* __restrict__ se) {
    __shared__ __align__(16) float mdl[8][32][17];
    __shared__ int   mil[8][32][17];
    __shared__ float bbx[128][8];
    __shared__ float cmd[128];
    __shared__ float smd[128];
    __shared__ int   order_s[128];
    __shared__ unsigned thr[32];
    __shared__ float gbox[6];
    __shared__ int   stop_s;
    uint2 (*buf)[256] = reinterpret_cast<uint2(*)[256]>(&mdl[0][0][0]);  // overlay, 14336B < 17408B

    int t = threadIdx.x;
    int b = blockIdx.x >> 8;
    int qbase = (blockIdx.x & 255) * 32;
    int ql = t & 31, part = t >> 5;
    const float4* cb_ = cps + ((size_t)b << 13);
    const int* ob_ = oidx + (b << 13);
    float4 qc = cb_[qbase + ql];

    for (int e = t; e < 1024; e += 256) ((float*)bbx)[e] = bboxg[(b << 10) + e];
    if (t < 32) thr[t] = encf(FLT_MAX);
    if (t < 64) {   // group bbox (lanes 32-63 duplicate queries -> full-wave reduce ok)
        float lox = qc.x, hix = qc.x, loy = qc.y, hiy = qc.y, loz = qc.z, hiz = qc.z;
        for (int o = 32; o > 0; o >>= 1) {
            lox = fminf(lox, __shfl_down(lox, o)); hix = fmaxf(hix, __shfl_down(hix, o));
            loy = fminf(loy, __shfl_down(loy, o)); hiy = fmaxf(hiy, __shfl_down(hiy, o));
            loz = fminf(loz, __shfl_down(loz, o)); hiz = fmaxf(hiz, __shfl_down(hiz, o));
        }
        if (t == 0) { gbox[0] = lox; gbox[1] = loy; gbox[2] = loz; gbox[3] = hix; gbox[4] = hiy; gbox[5] = hiz; }
    }
    __syncthreads();

    if (t < 128) cmd[t] = bb_md2(gbox, &bbx[t][0]);
    __syncthreads();
    if (t < 128) {   // rank sort (stable by chunk idx)
        float v = cmd[t]; int rank = 0;
        for (int j = 0; j < 128; ++j) {
            float u = cmd[j];
            rank += (u < v) || (u == v && j < t);
        }
        order_s[rank] = t; smd[rank] = v;
    }
    __syncthreads();

    float dl[16]; int il[16];
#pragma unroll
    for (int i = 0; i < 16; ++i) { dl[i] = FLT_MAX; il[i] = 0x7fffffff; }

    // seed: first 16 candidates of partition's round-0 chunk
    int cseed = order_s[part];
    {
        int j0 = cseed * 64;
#pragma unroll
        for (int k = 0; k < 16; ++k) {
            float d = dist2(qc, cb_[j0 + k]);
            int o = ob_[j0 + k];
            if (d < dl[15] || (d == dl[15] && o < il[15])) ins16_lex(dl, il, d, o);
        }
    }
    atomicMin(&thr[ql], encf(dl[15]));
    float Tf = dl[15];
    unsigned te = thr[ql];
    int cnt = 0;

    for (int r = 0; r < 16; ++r) {
        int c = order_s[8 * r + part];
        float md2v = md2box(qc, &bbx[c][0]);
        bool need = md2v <= Tf * 1.001f + 1e-3f;   // conservative (covers expansion-formula fp error)
        if (__any(need)) {
            int jb = c * 64 + (r == 0 ? 16 : 0);
            int je = c * 64 + 64;
            float4 n0 = cb_[jb], n1 = cb_[jb + 1], n2 = cb_[jb + 2], n3 = cb_[jb + 3];
            for (int j = jb; j < je; j += 4) {
                float4 c0_ = n0, c1_ = n1, c2_ = n2, c3_ = n3;
                n0 = cb_[j + 4]; n1 = cb_[j + 5]; n2 = cb_[j + 6]; n3 = cb_[j + 7]; // tail over-read stays in padded ws
                float d0 = dist2(qc, c0_), d1 = dist2(qc, c1_), d2v = dist2(qc, c2_), d3 = dist2(qc, c3_);
                bool p0 = d0 <= Tf, p1 = d1 <= Tf, p2 = d2v <= Tf, p3 = d3 <= Tf;
                if (__any(p0 | p1 | p2 | p3)) {
                    if (p0) { buf[cnt][t] = make_uint2(__float_as_uint(d0), (unsigned)j); ++cnt; }
                    if (p1) { buf[cnt][t] = make_uint2(__float_as_uint(d1), (unsigned)(j + 1)); ++cnt; }
                    if (p2) { buf[cnt][t] = make_uint2(__float_as_uint(d2v), (unsigned)(j + 2)); ++cnt; }
                    if (p3) { buf[cnt][t] = make_uint2(__float_as_uint(d3), (unsigned)(j + 3)); ++cnt; }
                    if (__any(cnt >= 4)) {
                        unsigned jj[7]; int oid[7];
#pragma unroll
                        for (int q2 = 0; q2 < 7; ++q2) jj[q2] = (q2 < cnt) ? buf[q2][t].y : 0u;
#pragma unroll
                        for (int q2 = 0; q2 < 7; ++q2) oid[q2] = ob_[jj[q2]];
#pragma unroll
                        for (int q2 = 0; q2 < 7; ++q2) {
                            if (q2 < cnt) {
                                float d = __uint_as_float(buf[q2][t].x); int o = oid[q2];
                                if (d < dl[15] || (d == dl[15] && o < il[15])) ins16_lex(dl, il, d, o);
                            }
                        }
                        cnt = 0;
                        atomicMin(&thr[ql], encf(dl[15]));
                    }
                }
                Tf = fminf(Tf, decf(te));
                te = thr[ql];
            }
        }
        atomicMin(&thr[ql], encf(dl[15]));
        __syncthreads();
        if (t == 0) {
            float mt = 0.f;
            for (int i = 0; i < 32; ++i) mt = fmaxf(mt, decf(thr[i]));
            stop_s = (r == 15) || (smd[8 * (r + 1)] > mt * 1.001f + 1e-3f);
        }
        __syncthreads();
        if (stop_s) break;
        Tf = fminf(Tf, decf(thr[ql]));
        te = thr[ql];
    }
    if (__any(cnt > 0)) {   // final flush
        unsigned jj[7]; int oid[7];
#pragma unroll
        for (int q2 = 0; q2 < 7; ++q2) jj[q2] = (q2 < cnt) ? buf[q2][t].y : 0u;
#pragma unroll
        for (int q2 = 0; q2 < 7; ++q2) oid[q2] = ob_[jj[q2]];
#pragma unroll
        for (int q2 = 0; q2 < 7; ++q2) {
            if (q2 < cnt) {
                float d = __uint_as_float(buf[q2][t].x); int o = oid[q2];
                if (d < dl[15] || (d == dl[15] && o < il[15])) ins16_lex(dl, il, d, o);
            }
        }
    }

    __syncthreads();   // protect buf -> mdl overlay
#pragma unroll
    for (int i = 0; i < 16; ++i) { mdl[part][ql][i] = dl[i]; mil[part][ql][i] = il[i]; }
    mdl[part][ql][16] = FLT_MAX; mil[part][ql][16] = 0x7fffffff;  // merge sentinel
    __syncthreads();

    // 8-way streaming merge: one thread per query picks lex-min 16 times
    if (t < 32) {
        int hp[8]; float hd[8]; int hi_[8];
#pragma unroll
        for (int p = 0; p < 8; ++p) { hp[p] = 0; hd[p] = mdl[p][t][0]; hi_[p] = mil[p][t][0]; }
        float od[16]; int oi[16];
#pragma unroll
        for (int s = 0; s < 16; ++s) {
            float bd = hd[0]; int bi_ = hi_[0]; int bp = 0;
#pragma unroll
            for (int p = 1; p < 8; ++p) {
                bool cc = (hd[p] < bd) || (hd[p] == bd && hi_[p] < bi_);
                bd = cc ? hd[p] : bd; bi_ = cc ? hi_[p] : bi_; bp = cc ? p : bp;
            }
            od[s] = bd; oi[s] = bi_;
#pragma unroll
            for (int p = 0; p < 8; ++p) {
                if (p == bp) { ++hp[p]; hd[p] = mdl[p][t][hp[p]]; hi_[p] = mil[p][t][hp[p]]; }
            }
        }
#pragma unroll
        for (int s = 0; s < 16; ++s) { mdl[0][t][s] = od[s]; mil[0][t][s] = oi[s]; }
    }
    __syncthreads();

    // epilogue: write se rows (scatter to original query index)
    for (int s2 = t; s2 < 512; s2 += 256) {
        int qq = s2 >> 4, k = s2 & 15;
        float d2s = mdl[0][qq][k]; int oid = mil[0][qq][k];
        float4 qc2 = cb_[qbase + qq];
        int oq = ob_[qbase + qq];
        float4 nb = cp4[(b << 13) + oid];
        float dist = sqrtf(fmaxf(d2s, 1e-12f));
        float* sp = se + ((size_t)(b * NN + oq) * KK + k) * 10;
        sp[0] = qc2.x; sp[1] = qc2.y; sp[2] = qc2.z;
        sp[3] = nb.x;  sp[4] = nb.y;  sp[5] = nb.z;
        sp[6] = qc2.x - nb.x; sp[7] = qc2.y - nb.y; sp[8] = qc2.z - nb.z;
        sp[9] = dist;
    }
}

// ---------------- K2: mlp1 + shortcut linear + shortcut BN stats ----------------
__global__ __launch_bounds__(128) void k_feat(const float* __restrict__ feat,
                                              const float* __restrict__ Wm1, const float* __restrict__ bm1,
                                              const float* __restrict__ Wsh, const float* __restrict__ bsh,
                                              float* __restrict__ xf, float* __restrict__ short_pre,
                                              double* __restrict__ stats) {
    __shared__ float fl[32][33];
    int t = threadIdx.x;
    int pbase = blockIdx.x * 32;
    float wcol[32];
#pragma unroll
    for (int i = 0; i < 32; ++i) wcol[i] = Wsh[i * C2 + t];
    float wm[32];
    if (t < 32) {
#pragma unroll
        for (int i = 0; i < 32; ++i) wm[i] = Wm1[i * HH + t];
    }
    float bs = bsh[t];
    float bm = (t < 32) ? bm1[t] : 0.f;
    double s = 0.0, s2 = 0.0;

    for (int e = t; e < 1024; e += 128) {
        int p = e >> 5, i = e & 31;
        fl[p][i] = feat[(size_t)(pbase + p) * CIN + i];
    }
    __syncthreads();
    for (int p = 0; p < 32; ++p) {
        float acc = bs;
#pragma unroll
        for (int i = 0; i < 32; ++i) acc += fl[p][i] * wcol[i];
        int gp = pbase + p;
        short_pre[(size_t)gp * C2 + t] = acc;
        s += acc; s2 += (double)acc * acc;
        if (t < 32) {
            float xv = bm;
#pragma unroll
            for (int i = 0; i < 32; ++i) xv += fl[p][i] * wm[i];
            xf[(size_t)gp * HH + t] = xv >= 0.f ? xv : 0.2f * xv;
        }
    }
    atomicAdd(&stats[S_SHORT + t], s);
    atomicAdd(&stats[S_SHORT + C2 + t], s2);
}

// ---------------- K3: lse1+lse2 linear BN stats (LDS-staged) ----------------
__global__ __launch_bounds__(256) void k_lse_stats(const float* __restrict__ se,
                                                   const float* __restrict__ W1, const float* __restrict__ b1,
                                                   const float* __restrict__ W2, const float* __restrict__ b2,
                                                   double* __restrict__ stats) {
    __shared__ float srows[256][10];
    __shared__ double red[4][64][2];
    int t = threadIdx.x;
    int c = t & 63, grp = t >> 6;
    int ch = c & 31; bool second = c >= 32;
    const float* W = second ? W2 : W1;
    float wcol[10];
#pragma unroll
    for (int d = 0; d < 10; ++d) wcol[d] = W[d * HH + ch];
    float bb = second ? b2[ch] : b1[ch];
    double s = 0.0, s2 = 0.0;
    int rbase = blockIdx.x * 512;

    for (int tile = 0; tile < 2; ++tile) {
        __syncthreads();
        const float* src = se + (size_t)(rbase + tile * 256) * 10;
        for (int e = t; e < 2560; e += 256) srows[e / 10][e % 10] = src[e];
        __syncthreads();
        int r0 = grp * 64;
        for (int r = r0; r < r0 + 64; ++r) {
            float acc = bb;
#pragma unroll
            for (int d = 0; d < 10; ++d) acc += srows[r][d] * wcol[d];
            s += acc; s2 += (double)acc * acc;
        }
    }
    red[grp][c][0] = s; red[grp][c][1] = s2;
    __syncthreads();
    if (grp == 0) {
        for (int g = 1; g < 4; ++g) { s += red[g][c][0]; s2 += red[g][c][1]; }
        int base = second ? S_LSE2 : S_LSE1;
        atomicAdd(&stats[base + ch], s);
        atomicAdd(&stats[base + 32 + ch], s2);
    }
}

// BN scale/shift from raw stats (computed redundantly in consumer prologues)
DEV float2 fin_pair(const double* stats, int sbase, int ch, int nch, double M,
                    const float* g, const float* be) {
    double mean = stats[sbase + ch] / M;
    double var = stats[sbase + nch + ch] / M - mean * mean;
    double scd = (double)g[ch] / sqrt(var + (double)EPSF);
    return make_float2((float)scd, (float)((double)be[ch] - mean * scd));
}

// ---------------- K5/K7: fused LocSE + attentive pooling + MLP ----------------
template <int OUTC, bool SECOND>
__global__ __launch_bounds__(256) void k_att(const float* __restrict__ se,
                                             const float* __restrict__ featsrc,
                                             const float* __restrict__ Wlse, const float* __restrict__ blse,
                                             const float* __restrict__ Wlin,
                                             const float* __restrict__ Wmlp, const float* __restrict__ bmlp,
                                             double* __restrict__ stats, int lse_sbase, int feat_sbase, int stat_base,
                                             const float* __restrict__ g_lse, const float* __restrict__ be_lse,
                                             const float* __restrict__ g_f, const float* __restrict__ be_f,
                                             float* __restrict__ preout) {
    __shared__ __align__(16) float wlt[64][68];
    __shared__ float wm[64][OUTC];
    __shared__ __align__(16) float x1[4][16][40];
    __shared__ float fv[4][32];
    __shared__ float p1b[4][64];
    __shared__ double red[4][OUTC][2];

    int t = threadIdx.x, w = t >> 6, c = t & 63;
    int ch = c & 31, half = c >> 5;
    for (int e = t; e < 4096; e += 256) wlt[e & 63][e >> 6] = Wlin[e];
    for (int e = t; e < 64 * OUTC; e += 256) wm[e / OUTC][e % OUTC] = Wmlp[e];

    float wf[10]; float bf;
    {
        float2 p = fin_pair(stats, lse_sbase, ch, 32, (double)BNKROWS, g_lse, be_lse);
#pragma unroll
        for (int d = 0; d < 10; ++d) wf[d] = Wlse[d * 32 + ch] * p.x;
        bf = blse[ch] * p.x + p.y;
    }
    float fa = 1.f, fb = 0.f;
    if (SECOND && c >= 32) {
        float2 p = fin_pair(stats, feat_sbase, ch, 32, (double)BNTOT, g_f, be_f);
        fa = p.x; fb = p.y;
    }
    double s = 0.0, s2 = 0.0;
    __syncthreads();

    for (int i = 0; i < 8; ++i) {
        int p = blockIdx.x * 32 + w * 8 + i;

        int kbase = half * 8;
        const float* sp = se + (size_t)p * (KK * 10) + kbase * 10;
        float myv[8];
#pragma unroll
        for (int kk = 0; kk < 8; ++kk) {
            float acc = bf;
#pragma unroll
            for (int d = 0; d < 10; ++d) acc += sp[kk * 10 + d] * wf[d];
            myv[kk] = fmaxf(acc, 0.f);
        }
#pragma unroll
        for (int kk = 0; kk < 8; ++kk) x1[w][kbase + kk][ch] = myv[kk];

        float xv = 0.f;
        if (c >= 32) {
            xv = featsrc[(size_t)p * 32 + ch];
            if (SECOND) xv = fmaxf(xv * fa + fb, 0.f);
            fv[w][ch] = xv;
        }

        float col[16];
        if (c < 32) {
#pragma unroll
            for (int kk = 0; kk < 8; ++kk) col[kk] = myv[kk];
#pragma unroll
            for (int kk = 0; kk < 8; ++kk) col[8 + kk] = x1[w][8 + kk][ch];
        } else {
#pragma unroll
            for (int k = 0; k < 16; ++k) col[k] = xv;
        }

        float cst = 0.f;
#pragma unroll
        for (int dg = 8; dg < 16; ++dg) {
            float4 wv = *(const float4*)&wlt[c][dg * 4];
            float4 xvv = *(const float4*)&fv[w][(dg - 8) * 4];
            cst += xvv.x * wv.x + xvv.y * wv.y + xvv.z * wv.z + xvv.w * wv.w;
        }
        float scv[16];
#pragma unroll
        for (int k = 0; k < 16; ++k) scv[k] = cst;
        for (int dg = 0; dg < 8; ++dg) {
            float4 wv = *(const float4*)&wlt[c][dg * 4];
#pragma unroll
            for (int k = 0; k < 16; ++k) {
                float4 xvv = *(const float4*)&x1[w][k][dg * 4];
                scv[k] += xvv.x * wv.x + xvv.y * wv.y + xvv.z * wv.z + xvv.w * wv.w;
            }
        }
        float m = scv[0];
#pragma unroll
        for (int k = 1; k < 16; ++k) m = fmaxf(m, scv[k]);
        float sum = 0.f, p1 = 0.f;
#pragma unroll
        for (int k = 0; k < 16; ++k) { float e = __expf(scv[k] - m); sum += e; p1 += e * col[k]; }
        p1 /= sum;
        p1b[w][c] = p1;

        if (c < OUTC) {
            float acc = bmlp[c];
#pragma unroll
            for (int d = 0; d < 64; ++d) acc += p1b[w][d] * wm[d][c];
            preout[(size_t)p * OUTC + c] = acc;
            s += acc; s2 += (double)acc * acc;
        }
    }
    if (c < OUTC) { red[w][c][0] = s; red[w][c][1] = s2; }
    __syncthreads();
    if (t < OUTC) {
        double ts = red[0][t][0], ts2 = red[0][t][1];
        for (int g = 1; g < 4; ++g) { ts += red[g][t][0]; ts2 += red[g][t][1]; }
        atomicAdd(&stats[stat_base + t], ts);
        atomicAdd(&stats[stat_base + OUTC + t], ts2);
    }
}

// ---------------- K9: final mlp2 + shortcut BN + residual leaky + transposed write ----
__global__ __launch_bounds__(256) void k_out(const float* __restrict__ pre2,
                                             const float* __restrict__ short_pre,
                                             const float* __restrict__ W2, const float* __restrict__ b2,
                                             const double* __restrict__ stats,
                                             const float* __restrict__ g_a2, const float* __restrict__ be_a2,
                                             const float* __restrict__ g_s, const float* __restrict__ be_s,
                                             float* __restrict__ out) {
    __shared__ __align__(16) float w2[64][128];
    __shared__ float sc2[64], sh2[64], scs[128], shs[128], bb[128];
    int t = threadIdx.x;
    int pl = t & 63, seg = t >> 6;
    for (int e = t; e < 8192; e += 256) w2[e >> 7][e & 127] = W2[e];
    if (t < 64) { float2 p = fin_pair(stats, S_ATT2, t, 64, (double)BNTOT, g_a2, be_a2); sc2[t] = p.x; sh2[t] = p.y; }
    if (t >= 64 && t < 192) { int ch = t - 64; float2 p = fin_pair(stats, S_SHORT, ch, 128, (double)BNTOT, g_s, be_s); scs[ch] = p.x; shs[ch] = p.y; }
    if (t < 128) bb[t] = b2[t];
    __syncthreads();

    int p = blockIdx.x * 64 + pl;
    int b = p >> 13, n = p & 8191;
    const float* pr = pre2 + (size_t)p * 64;
    float xa[64];
#pragma unroll
    for (int c = 0; c < 64; c += 4) {
        float4 v = *(const float4*)&pr[c];
        xa[c + 0] = fmaxf(v.x * sc2[c + 0] + sh2[c + 0], 0.f);
        xa[c + 1] = fmaxf(v.y * sc2[c + 1] + sh2[c + 1], 0.f);
        xa[c + 2] = fmaxf(v.z * sc2[c + 2] + sh2[c + 2], 0.f);
        xa[c + 3] = fmaxf(v.w * sc2[c + 3] + sh2[c + 3], 0.f);
    }
    const float* shp = short_pre + (size_t)p * 128;
    int obase = seg * 32;
    for (int o = obase; o < obase + 32; o += 4) {
        float a0 = bb[o], a1 = bb[o + 1], a2 = bb[o + 2], a3 = bb[o + 3];
#pragma unroll
        for (int cc = 0; cc < 64; ++cc) {
            float4 wv = *(const float4*)&w2[cc][o];
            float x = xa[cc];
            a0 += x * wv.x; a1 += x * wv.y; a2 += x * wv.z; a3 += x * wv.w;
        }
        float4 sv = *(const float4*)&shp[o];
        float r0 = a0 + (sv.x * scs[o] + shs[o]);
        float r1 = a1 + (sv.y * scs[o + 1] + shs[o + 1]);
        float r2 = a2 + (sv.z * scs[o + 2] + shs[o + 2]);
        float r3 = a3 + (sv.w * scs[o + 3] + shs[o + 3]);
        out[((size_t)(b * C2 + o + 0)) * NN + n] = r0 >= 0.f ? r0 : 0.01f * r0;
        out[((size_t)(b * C2 + o + 1)) * NN + n] = r1 >= 0.f ? r1 : 0.01f * r1;
        out[((size_t)(b * C2 + o + 2)) * NN + n] = r2 >= 0.f ? r2 : 0.01f * r2;
        out[((size_t)(b * C2 + o + 3)) * NN + n] = r3 >= 0.f ? r3 : 0.01f * r3;
    }
}

extern "C" void kernel_launch(void* const* d_in, const int* in_sizes, int n_in,
                              void* d_out, int out_size, void* d_ws, size_t ws_size,
                              hipStream_t stream) {
    const float* coords    = (const float*)d_in[0];
    const float* features  = (const float*)d_in[1];
    const float* W_mlp1    = (const float*)d_in[2];
    const float* b_mlp1    = (const float*)d_in[3];
    const float* W_lse1    = (const float*)d_in[4];
    const float* b_lse1    = (const float*)d_in[5];
    const float* g_lse1    = (const float*)d_in[6];
    const float* be_lse1   = (const float*)d_in[7];
    const float* W_att1_lin= (const float*)d_in[8];
    const float* W_att1_mlp= (const float*)d_in[9];
    const float* b_att1_mlp= (const float*)d_in[10];
    const float* g_att1    = (const float*)d_in[11];
    const float* be_att1   = (const float*)d_in[12];
    const float* W_lse2    = (const float*)d_in[13];
    const float* b_lse2    = (const float*)d_in[14];
    const float* g_lse2    = (const float*)d_in[15];
    const float* be_lse2   = (const float*)d_in[16];
    const float* W_att2_lin= (const float*)d_in[17];
    const float* W_att2_mlp= (const float*)d_in[18];
    const float* b_att2_mlp= (const float*)d_in[19];
    const float* g_att2    = (const float*)d_in[20];
    const float* be_att2   = (const float*)d_in[21];
    const float* W_mlp2    = (const float*)d_in[22];
    const float* b_mlp2    = (const float*)d_in[23];
    const float* W_short   = (const float*)d_in[24];
    const float* b_short   = (const float*)d_in[25];
    const float* g_short   = (const float*)d_in[26];
    const float* be_short  = (const float*)d_in[27];

    float* ws = (float*)d_ws;
    float4* cp4      = (float4*)(ws + OFF_CP4);
    float* se        = ws + OFF_SE;
    float* xf        = ws + OFF_XF;
    float* short_pre = ws + OFF_SHORT;
    float* pre1      = ws + OFF_PRE1;
    float* pre2      = ws + OFF_PRE2;
    double* stats    = (double*)(ws + OFF_STATS);
    int* counts      = (int*)(ws + OFF_COUNTS);
    int* code        = (int*)(ws + OFF_CODE);
    float4* cps      = (float4*)(ws + OFF_CPS);
    int* oidxArr     = (int*)(ws + OFF_OIDX);
    float* bboxg     = ws + OFF_BBOX;
    float* out       = (float*)d_out;

    hipMemsetAsync(stats, 0, S_TOTAL * 8 + 2 * NCELL * 4, stream);

    k_prep<<<BNTOT / 256, 256, 0, stream>>>(coords, cp4, code, counts);
    k_scan<<<1, 256, 0, stream>>>(counts);
    k_scatter<<<BNTOT / 256, 256, 0, stream>>>(cp4, code, counts, cps, oidxArr);
    k_bbox<<<BB * NCHUNK, 64, 0, stream>>>(cps, bboxg);
    k_knn<<<512, 256, 0, stream>>>(cps, oidxArr, cp4, bboxg, se);
    k_feat<<<512, 128, 0, stream>>>(features, W_mlp1, b_mlp1, W_short, b_short,
                                    xf, short_pre, stats);
    k_lse_stats<<<512, 256, 0, stream>>>(se, W_lse1, b_lse1, W_lse2, b_lse2, stats);
    k_att<32, false><<<512, 256, 0, stream>>>(se, xf, W_lse1, b_lse1, W_att1_lin,
                                              W_att1_mlp, b_att1_mlp, stats,
                                              S_LSE1, 0, S_ATT1,
                                              g_lse1, be_lse1, nullptr, nullptr, pre1);
    k_att<64, true><<<512, 256, 0, stream>>>(se, pre1, W_lse2, b_lse2, W_att2_lin,
                                             W_att2_mlp, b_att2_mlp, stats,
                                             S_LSE2, S_ATT1, S_ATT2,
                                             g_lse2, be_lse2, g_att1, be_att1, pre2);
    k_out<<<BNTOT / 64, 256, 0, stream>>>(pre2, short_pre, W_mlp2, b_mlp2, stats,
                                          g_att2, be_att2, g_short, be_short, out);
}

// Round 8
// 677.475 us; speedup vs baseline: 1.1941x; 1.1752x over previous
//
#include <hip/hip_runtime.h>
#include <cfloat>
#include <cmath>

#define DEV __device__ __forceinline__

constexpr int BB = 2, NN = 8192, KK = 16, CIN = 32, HH = 32, CO = 64, C2 = 128;
constexpr int BNTOT = BB * NN;        // 16384
constexpr int BNKROWS = BB * NN * KK; // 262144
constexpr float EPSF = 1e-6f;
constexpr int NCELL = 4096;           // 16^3 morton cells
constexpr int NCHUNK = 128;           // 8192/64 chunks per batch

// stats indices (doubles): [sum.., sumsq..] per group
constexpr int S_LSE1 = 0, S_LSE2 = 64, S_ATT1 = 128, S_ATT2 = 192, S_SHORT = 320, S_TOTAL = 576;

// workspace layout (in floats)
constexpr size_t OFF_CP4   = 0;                                  // orig-order (x,y,z,sq): 16384*4
constexpr size_t OFF_SE    = OFF_CP4 + (size_t)BNTOT * 4;        // se (B,N,K,10)
constexpr size_t OFF_XF    = OFF_SE + (size_t)BNKROWS * 10;      // mlp1 out (B,N,32)
constexpr size_t OFF_SHORT = OFF_XF + (size_t)BNTOT * HH;        // shortcut pre-BN (B,N,128)
constexpr size_t OFF_PRE1  = OFF_SHORT + (size_t)BNTOT * C2;     // att1 pre-BN (B,N,32)
constexpr size_t OFF_PRE2  = OFF_PRE1 + (size_t)BNTOT * HH;      // att2 pre-BN (B,N,64)
constexpr size_t OFF_STATS = OFF_PRE2 + (size_t)BNTOT * CO;      // doubles x576
constexpr size_t OFF_COUNTS= OFF_STATS + 2 * S_TOTAL;            // int[2][4096]
// sort scratch overlaid inside the SHORT region (dead until k_feat, which runs after k_knn)
constexpr size_t OFF_CODE  = OFF_SHORT;                          // int[16384]
constexpr size_t OFF_CPS   = OFF_CODE + 16384;                   // float4[2][8192] + 4 pad
constexpr size_t OFF_OIDX  = OFF_CPS + (size_t)BNTOT * 4 + 16;   // int[2][8192]
constexpr size_t OFF_BBOX  = OFF_OIDX + 16384;                   // float[256][8]

DEV unsigned spr3(unsigned v) {
    return (v & 1u) | ((v & 2u) << 2) | ((v & 4u) << 4) | ((v & 8u) << 6);
}

// ---------------- K0: pack (x,y,z,sq) + morton cell + counts ----------------
__global__ __launch_bounds__(256) void k_prep(const float* __restrict__ coords,
                                              float4* __restrict__ cp4,
                                              int* __restrict__ code, int* __restrict__ counts) {
#pragma clang fp contract(off)
    int i = blockIdx.x * 256 + threadIdx.x;
    if (i >= BNTOT) return;
    float x = coords[3 * i], y = coords[3 * i + 1], z = coords[3 * i + 2];
    float sq = (x * x + y * y) + z * z;   // match numpy sum order, no FMA
    cp4[i] = make_float4(x, y, z, sq);
    const float inv = 16.f / 8.8f;
    int ix = min(15, max(0, (int)floorf((x + 4.4f) * inv)));
    int iy = min(15, max(0, (int)floorf((y + 4.4f) * inv)));
    int iz = min(15, max(0, (int)floorf((z + 4.4f) * inv)));
    unsigned m = spr3(ix) | (spr3(iy) << 1) | (spr3(iz) << 2);
    code[i] = (int)m;
    atomicAdd(&counts[((i >> 13) << 12) + m], 1);
}

// ---------------- K0b: exclusive prefix scan of counts (per batch) ----------------
__global__ __launch_bounds__(256) void k_scan(int* __restrict__ counts) {
    __shared__ int lds[256];
    int t = threadIdx.x;
    for (int b = 0; b < 2; ++b) {
        int base = b * NCELL;
        int v[16]; int s = 0;
#pragma unroll
        for (int k = 0; k < 16; ++k) { int tmp = counts[base + t * 16 + k]; v[k] = s; s += tmp; }
        lds[t] = s;
        __syncthreads();
        for (int o = 1; o < 256; o <<= 1) {
            int u = (t >= o) ? lds[t - o] : 0;
            __syncthreads();
            lds[t] += u;
            __syncthreads();
        }
        int off = lds[t] - s;   // exclusive
#pragma unroll
        for (int k = 0; k < 16; ++k) counts[base + t * 16 + k] = off + v[k];
        __syncthreads();
    }
}

// ---------------- K0c: scatter into sorted order ----------------
__global__ __launch_bounds__(256) void k_scatter(const float4* __restrict__ cp4,
                                                 const int* __restrict__ code,
                                                 int* __restrict__ cursor,
                                                 float4* __restrict__ cps, int* __restrict__ oidx) {
    int i = blockIdx.x * 256 + threadIdx.x;
    if (i >= BNTOT) return;
    int b = i >> 13, n = i & 8191;
    int c = code[i];
    int pos = atomicAdd(&cursor[(b << 12) + c], 1);
    cps[(b << 13) + pos] = cp4[i];
    oidx[(b << 13) + pos] = n;
}

// ---------------- K0d: per-chunk bbox ----------------
__global__ __launch_bounds__(64) void k_bbox(const float4* __restrict__ cps,
                                             float* __restrict__ bboxg) {
    int c = blockIdx.x, lane = threadIdx.x;
    float4 p = cps[c * 64 + lane];
    float lox = p.x, hix = p.x, loy = p.y, hiy = p.y, loz = p.z, hiz = p.z;
    for (int o = 32; o > 0; o >>= 1) {
        lox = fminf(lox, __shfl_down(lox, o)); hix = fmaxf(hix, __shfl_down(hix, o));
        loy = fminf(loy, __shfl_down(loy, o)); hiy = fmaxf(hiy, __shfl_down(hiy, o));
        loz = fminf(loz, __shfl_down(loz, o)); hiz = fmaxf(hiz, __shfl_down(hiz, o));
    }
    if (lane == 0) {
        float* bb = bboxg + c * 8;
        bb[0] = lox; bb[1] = loy; bb[2] = loz; bb[3] = hix; bb[4] = hiy; bb[5] = hiz;
    }
}

DEV float dist2(float4 qc, float4 c) {
#pragma clang fp contract(off)
    float dot = (qc.x * c.x + qc.y * c.y) + qc.z * c.z;
    return (qc.w + c.w) - 2.0f * dot;   // exact jax/np expansion formula
}

DEV float md2box(float4 q, float lox, float loy, float loz, float hix, float hiy, float hiz) {
    float dx = fmaxf(0.f, fmaxf(lox - q.x, q.x - hix));
    float dy = fmaxf(0.f, fmaxf(loy - q.y, q.y - hiy));
    float dz = fmaxf(0.f, fmaxf(loz - q.z, q.z - hiz));
    return dx * dx + dy * dy + dz * dz;
}

DEV float bb_md2(const float* A, const float* B) {   // box-to-box min dist^2 (lo0..2, hi3..5)
    float dx = fmaxf(0.f, fmaxf(B[0] - A[3], A[0] - B[3]));
    float dy = fmaxf(0.f, fmaxf(B[1] - A[4], A[1] - B[4]));
    float dz = fmaxf(0.f, fmaxf(B[2] - A[5], A[2] - B[5]));
    return dx * dx + dy * dy + dz * dz;
}

// order-preserving float->uint encoding
DEV unsigned encf(float f) {
    unsigned u = __float_as_uint(f);
    return (u & 0x80000000u) ? ~u : (u | 0x80000000u);
}
DEV float decf(unsigned e) {
    unsigned u = (e & 0x80000000u) ? (e & 0x7FFFFFFFu) : ~e;
    return __uint_as_float(u);
}

// lexicographic (d, orig-idx) sorted insert
DEV void ins16_lex(float (&dl)[16], int (&il)[16], float d, int id) {
    float dk = d; int jk = id;
#pragma unroll
    for (int r = 0; r < 16; ++r) {
        bool c = (dk < dl[r]) || (dk == dl[r] && jk < il[r]);
        float td = dl[r]; int ti = il[r];
        dl[r] = c ? dk : dl[r]; il[r] = c ? jk : il[r];
        dk = c ? td : dk; jk = c ? ti : jk;
    }
}

// ---------------- K1: wave-autonomous pruned KNN + spatial encoding ----------------
// grid 512 = 2 batches x 256 groups of 32 sorted queries; block 256 = 4 waves.
// All 128 chunks rank-ordered once (nearest-first vs group query bbox, box-to-box
// md2). Wave w independently walks order[w], order[w+4], ... with NO barriers:
// its 64 lanes = 32 queries x 2 candidate-halves (lane l: query l&31, half l>>5
// scans 32 of the chunk's 64 candidates). Per-query conservative thresholds thr[]
// shared across waves via LDS atomicMin (stale reads are larger -> safe). Wave
// stops when the next chunk's group-level md2 lower bound exceeds its max
// threshold. Selection keyed (formula-d2, orig idx) lex -> exact top_k semantics.
__global__ __launch_bounds__(256) void k_knn(const float4* __restrict__ cps,
                                             const int* __restrict__ oidx,
                                             const float4* __restrict__ cp4,
                                             const float* __restrict__ bboxg,
                                             float* __restrict__ se) {
    __shared__ __align__(16) float mdl[8][32][17];
    __shared__ int   mil[8][32][17];
    __shared__ float cmd[128];
    __shared__ float smd[128];
    __shared__ int   order_s[128];
    __shared__ unsigned thr[32];
    __shared__ float gbox[6];
    uint2 (*buf)[256] = reinterpret_cast<uint2(*)[256]>(&mdl[0][0][0]);  // overlay, 14336B < 17408B

    int t = threadIdx.x;
    int b = blockIdx.x >> 8;
    int qbase = (blockIdx.x & 255) * 32;
    int ql = t & 31;
    int part = t >> 5;          // 0..7 = (wave, half)
    int wv = t >> 6;            // 0..3
    int half = (t >> 5) & 1;
    const float4* cb_ = cps + ((size_t)b << 13);
    const int* ob_ = oidx + (b << 13);
    const float* bbase = bboxg + (b << 10);
    float4 qc = cb_[qbase + ql];

    if (t < 32) thr[t] = encf(FLT_MAX);
    if (t < 64) {   // group bbox over the 32 queries (lanes 32-63 duplicate -> reduce ok)
        float lox = qc.x, hix = qc.x, loy = qc.y, hiy = qc.y, loz = qc.z, hiz = qc.z;
        for (int o = 32; o > 0; o >>= 1) {
            lox = fminf(lox, __shfl_down(lox, o)); hix = fmaxf(hix, __shfl_down(hix, o));
            loy = fminf(loy, __shfl_down(loy, o)); hiy = fmaxf(hiy, __shfl_down(hiy, o));
            loz = fminf(loz, __shfl_down(loz, o)); hiz = fmaxf(hiz, __shfl_down(hiz, o));
        }
        if (t == 0) { gbox[0] = lox; gbox[1] = loy; gbox[2] = loz; gbox[3] = hix; gbox[4] = hiy; gbox[5] = hiz; }
    }
    __syncthreads();

    if (t < 128) cmd[t] = bb_md2(gbox, bbase + t * 8);
    __syncthreads();
    if (t < 128) {   // rank sort (stable by chunk idx)
        float v = cmd[t]; int rank = 0;
        for (int j = 0; j < 128; ++j) {
            float u = cmd[j];
            rank += (u < v) || (u == v && j < t);
        }
        order_s[rank] = t; smd[rank] = v;
    }
    __syncthreads();

    float dl[16]; int il[16];
#pragma unroll
    for (int i = 0; i < 16; ++i) { dl[i] = FLT_MAX; il[i] = 0x7fffffff; }

    float Tf = FLT_MAX;
    unsigned te = encf(FLT_MAX);
    int cnt = 0;

    // generic predicated scan of [jb, je) sorted candidates (buffered inserts)
    auto scan_range = [&](int jb, int je) {
        float4 n0 = cb_[jb], n1 = cb_[jb + 1], n2 = cb_[jb + 2], n3 = cb_[jb + 3];
        for (int j = jb; j < je; j += 4) {
            float4 c0_ = n0, c1_ = n1, c2_ = n2, c3_ = n3;
            n0 = cb_[j + 4]; n1 = cb_[j + 5]; n2 = cb_[j + 6]; n3 = cb_[j + 7]; // 64B tail over-read covered by ws pad
            float d0 = dist2(qc, c0_), d1 = dist2(qc, c1_), d2v = dist2(qc, c2_), d3 = dist2(qc, c3_);
            bool p0 = d0 <= Tf, p1 = d1 <= Tf, p2 = d2v <= Tf, p3 = d3 <= Tf;
            if (__any(p0 | p1 | p2 | p3)) {
                if (p0) { buf[cnt][t] = make_uint2(__float_as_uint(d0), (unsigned)j); ++cnt; }
                if (p1) { buf[cnt][t] = make_uint2(__float_as_uint(d1), (unsigned)(j + 1)); ++cnt; }
                if (p2) { buf[cnt][t] = make_uint2(__float_as_uint(d2v), (unsigned)(j + 2)); ++cnt; }
                if (p3) { buf[cnt][t] = make_uint2(__float_as_uint(d3), (unsigned)(j + 3)); ++cnt; }
                if (__any(cnt >= 4)) {
                    unsigned jj[7]; int oid[7];
#pragma unroll
                    for (int q2 = 0; q2 < 7; ++q2) jj[q2] = (q2 < cnt) ? buf[q2][t].y : 0u;
#pragma unroll
                    for (int q2 = 0; q2 < 7; ++q2) oid[q2] = ob_[jj[q2]];
#pragma unroll
                    for (int q2 = 0; q2 < 7; ++q2) {
                        if (q2 < cnt) {
                            float d = __uint_as_float(buf[q2][t].x); int o = oid[q2];
                            if (d < dl[15] || (d == dl[15] && o < il[15])) ins16_lex(dl, il, d, o);
                        }
                    }
                    cnt = 0;
                    atomicMin(&thr[ql], encf(dl[15]));
                }
            }
            Tf = fminf(Tf, decf(te));
            te = thr[ql];
        }
    };

    // seed: wave's first chunk; first 16 of this lane's 32-candidate half unconditional
    {
        int c0 = order_s[wv];
        int jb = c0 * 64 + half * 32;
#pragma unroll
        for (int k = 0; k < 16; ++k) {
            float d = dist2(qc, cb_[jb + k]);
            ins16_lex(dl, il, d, ob_[jb + k]);
        }
        atomicMin(&thr[ql], encf(dl[15]));
        Tf = dl[15];
        te = thr[ql];
        scan_range(jb + 16, jb + 32);
    }
    atomicMin(&thr[ql], encf(dl[15]));

    // main loop: strided chunks, wave-autonomous, no barriers
    for (int s = wv + 4; s < 128; s += 4) {
        Tf = fminf(Tf, decf(thr[ql]));
        float mt = Tf;                                   // wave max over 32 queries (halves duplicate)
#pragma unroll
        for (int o = 1; o < 32; o <<= 1) mt = fmaxf(mt, __shfl_xor(mt, o));
        if (smd[s] > mt * 1.001f + 1e-3f) break;         // all later chunks pruned for every query
        int c = order_s[s];
        const float* bbp = bbase + c * 8;
        float lox = bbp[0], loy = bbp[1], loz = bbp[2], hix = bbp[3], hiy = bbp[4], hiz = bbp[5];
        float md2v = md2box(qc, lox, loy, loz, hix, hiy, hiz);
        bool need = md2v <= Tf * 1.001f + 1e-3f;         // margin covers expansion-formula fp error
        if (__any(need)) {
            int jb = c * 64 + half * 32;
            te = thr[ql];
            scan_range(jb, jb + 32);
            atomicMin(&thr[ql], encf(dl[15]));
        }
    }
    if (__any(cnt > 0)) {   // final flush
        unsigned jj[7]; int oid[7];
#pragma unroll
        for (int q2 = 0; q2 < 7; ++q2) jj[q2] = (q2 < cnt) ? buf[q2][t].y : 0u;
#pragma unroll
        for (int q2 = 0; q2 < 7; ++q2) oid[q2] = ob_[jj[q2]];
#pragma unroll
        for (int q2 = 0; q2 < 7; ++q2) {
            if (q2 < cnt) {
                float d = __uint_as_float(buf[q2][t].x); int o = oid[q2];
                if (d < dl[15] || (d == dl[15] && o < il[15])) ins16_lex(dl, il, d, o);
            }
        }
    }

    __syncthreads();   // protect buf -> mdl overlay
#pragma unroll
    for (int i = 0; i < 16; ++i) { mdl[part][ql][i] = dl[i]; mil[part][ql][i] = il[i]; }
    __syncthreads();

    // pairwise merge tree 8->4->2->1 (lex)
    for (int h2 = 4; h2 >= 1; h2 >>= 1) {
        if (part < h2) {
#pragma unroll
            for (int i = 0; i < 16; ++i) {
                float d = mdl[part + h2][ql][i]; int id = mil[part + h2][ql][i];
                if (d < dl[15] || (d == dl[15] && id < il[15])) ins16_lex(dl, il, d, id);
            }
#pragma unroll
            for (int i = 0; i < 16; ++i) { mdl[part][ql][i] = dl[i]; mil[part][ql][i] = il[i]; }
        }
        __syncthreads();
    }

    // epilogue: write se rows (scatter to original query index)
    for (int s2 = t; s2 < 512; s2 += 256) {
        int qq = s2 >> 4, k = s2 & 15;
        float d2s = mdl[0][qq][k]; int oid = mil[0][qq][k];
        float4 qc2 = cb_[qbase + qq];
        int oq = ob_[qbase + qq];
        float4 nb = cp4[(b << 13) + oid];
        float dist = sqrtf(fmaxf(d2s, 1e-12f));
        float* sp = se + ((size_t)(b * NN + oq) * KK + k) * 10;
        sp[0] = qc2.x; sp[1] = qc2.y; sp[2] = qc2.z;
        sp[3] = nb.x;  sp[4] = nb.y;  sp[5] = nb.z;
        sp[6] = qc2.x - nb.x; sp[7] = qc2.y - nb.y; sp[8] = qc2.z - nb.z;
        sp[9] = dist;
    }
}

// ---------------- K2: mlp1 + shortcut linear + shortcut BN stats ----------------
__global__ __launch_bounds__(128) void k_feat(const float* __restrict__ feat,
                                              const float* __restrict__ Wm1, const float* __restrict__ bm1,
                                              const float* __restrict__ Wsh, const float* __restrict__ bsh,
                                              float* __restrict__ xf, float* __restrict__ short_pre,
                                              double* __restrict__ stats) {
    __shared__ float fl[32][33];
    int t = threadIdx.x;
    int pbase = blockIdx.x * 32;
    float wcol[32];
#pragma unroll
    for (int i = 0; i < 32; ++i) wcol[i] = Wsh[i * C2 + t];
    float wm[32];
    if (t < 32) {
#pragma unroll
        for (int i = 0; i < 32; ++i) wm[i] = Wm1[i * HH + t];
    }
    float bs = bsh[t];
    float bm = (t < 32) ? bm1[t] : 0.f;
    double s = 0.0, s2 = 0.0;

    for (int e = t; e < 1024; e += 128) {
        int p = e >> 5, i = e & 31;
        fl[p][i] = feat[(size_t)(pbase + p) * CIN + i];
    }
    __syncthreads();
    for (int p = 0; p < 32; ++p) {
        float acc = bs;
#pragma unroll
        for (int i = 0; i < 32; ++i) acc += fl[p][i] * wcol[i];
        int gp = pbase + p;
        short_pre[(size_t)gp * C2 + t] = acc;
        s += acc; s2 += (double)acc * acc;
        if (t < 32) {
            float xv = bm;
#pragma unroll
            for (int i = 0; i < 32; ++i) xv += fl[p][i] * wm[i];
            xf[(size_t)gp * HH + t] = xv >= 0.f ? xv : 0.2f * xv;
        }
    }
    atomicAdd(&stats[S_SHORT + t], s);
    atomicAdd(&stats[S_SHORT + C2 + t], s2);
}

// ---------------- K3: lse1+lse2 linear BN stats (LDS-staged) ----------------
__global__ __launch_bounds__(256) void k_lse_stats(const float* __restrict__ se,
                                                   const float* __restrict__ W1, const float* __restrict__ b1,
                                                   const float* __restrict__ W2, const float* __restrict__ b2,
                                                   double* __restrict__ stats) {
    __shared__ float srows[256][10];
    __shared__ double red[4][64][2];
    int t = threadIdx.x;
    int c = t & 63, grp = t >> 6;
    int ch = c & 31; bool second = c >= 32;
    const float* W = second ? W2 : W1;
    float wcol[10];
#pragma unroll
    for (int d = 0; d < 10; ++d) wcol[d] = W[d * HH + ch];
    float bb = second ? b2[ch] : b1[ch];
    double s = 0.0, s2 = 0.0;
    int rbase = blockIdx.x * 512;

    for (int tile = 0; tile < 2; ++tile) {
        __syncthreads();
        const float* src = se + (size_t)(rbase + tile * 256) * 10;
        for (int e = t; e < 2560; e += 256) srows[e / 10][e % 10] = src[e];
        __syncthreads();
        int r0 = grp * 64;
        for (int r = r0; r < r0 + 64; ++r) {
            float acc = bb;
#pragma unroll
            for (int d = 0; d < 10; ++d) acc += srows[r][d] * wcol[d];
            s += acc; s2 += (double)acc * acc;
        }
    }
    red[grp][c][0] = s; red[grp][c][1] = s2;
    __syncthreads();
    if (grp == 0) {
        for (int g = 1; g < 4; ++g) { s += red[g][c][0]; s2 += red[g][c][1]; }
        int base = second ? S_LSE2 : S_LSE1;
        atomicAdd(&stats[base + ch], s);
        atomicAdd(&stats[base + 32 + ch], s2);
    }
}

// BN scale/shift from raw stats (computed redundantly in consumer prologues)
DEV float2 fin_pair(const double* stats, int sbase, int ch, int nch, double M,
                    const float* g, const float* be) {
    double mean = stats[sbase + ch] / M;
    double var = stats[sbase + nch + ch] / M - mean * mean;
    double scd = (double)g[ch] / sqrt(var + (double)EPSF);
    return make_float2((float)scd, (float)((double)be[ch] - mean * scd));
}

// ---------------- K5/K7: fused LocSE + attentive pooling + MLP ----------------
template <int OUTC, bool SECOND>
__global__ __launch_bounds__(256) void k_att(const float* __restrict__ se,
                                             const float* __restrict__ featsrc,
                                             const float* __restrict__ Wlse, const float* __restrict__ blse,
                                             const float* __restrict__ Wlin,
                                             const float* __restrict__ Wmlp, const float* __restrict__ bmlp,
                                             double* __restrict__ stats, int lse_sbase, int feat_sbase, int stat_base,
                                             const float* __restrict__ g_lse, const float* __restrict__ be_lse,
                                             const float* __restrict__ g_f, const float* __restrict__ be_f,
                                             float* __restrict__ preout) {
    __shared__ __align__(16) float wlt[64][68];
    __shared__ float wm[64][OUTC];
    __shared__ __align__(16) float x1[4][16][40];
    __shared__ float fv[4][32];
    __shared__ float p1b[4][64];
    __shared__ double red[4][OUTC][2];

    int t = threadIdx.x, w = t >> 6, c = t & 63;
    int ch = c & 31, half = c >> 5;
    for (int e = t; e < 4096; e += 256) wlt[e & 63][e >> 6] = Wlin[e];
    for (int e = t; e < 64 * OUTC; e += 256) wm[e / OUTC][e % OUTC] = Wmlp[e];

    float wf[10]; float bf;
    {
        float2 p = fin_pair(stats, lse_sbase, ch, 32, (double)BNKROWS, g_lse, be_lse);
#pragma unroll
        for (int d = 0; d < 10; ++d) wf[d] = Wlse[d * 32 + ch] * p.x;
        bf = blse[ch] * p.x + p.y;
    }
    float fa = 1.f, fb = 0.f;
    if (SECOND && c >= 32) {
        float2 p = fin_pair(stats, feat_sbase, ch, 32, (double)BNTOT, g_f, be_f);
        fa = p.x; fb = p.y;
    }
    double s = 0.0, s2 = 0.0;
    __syncthreads();

    for (int i = 0; i < 8; ++i) {
        int p = blockIdx.x * 32 + w * 8 + i;

        int kbase = half * 8;
        const float* sp = se + (size_t)p * (KK * 10) + kbase * 10;
        float myv[8];
#pragma unroll
        for (int kk = 0; kk < 8; ++kk) {
            float acc = bf;
#pragma unroll
            for (int d = 0; d < 10; ++d) acc += sp[kk * 10 + d] * wf[d];
            myv[kk] = fmaxf(acc, 0.f);
        }
#pragma unroll
        for (int kk = 0; kk < 8; ++kk) x1[w][kbase + kk][ch] = myv[kk];

        float xv = 0.f;
        if (c >= 32) {
            xv = featsrc[(size_t)p * 32 + ch];
            if (SECOND) xv = fmaxf(xv * fa + fb, 0.f);
            fv[w][ch] = xv;
        }

        float col[16];
        if (c < 32) {
#pragma unroll
            for (int kk = 0; kk < 8; ++kk) col[kk] = myv[kk];
#pragma unroll
            for (int kk = 0; kk < 8; ++kk) col[8 + kk] = x1[w][8 + kk][ch];
        } else {
#pragma unroll
            for (int k = 0; k < 16; ++k) col[k] = xv;
        }

        float cst = 0.f;
#pragma unroll
        for (int dg = 8; dg < 16; ++dg) {
            float4 wv = *(const float4*)&wlt[c][dg * 4];
            float4 xvv = *(const float4*)&fv[w][(dg - 8) * 4];
            cst += xvv.x * wv.x + xvv.y * wv.y + xvv.z * wv.z + xvv.w * wv.w;
        }
        float scv[16];
#pragma unroll
        for (int k = 0; k < 16; ++k) scv[k] = cst;
        for (int dg = 0; dg < 8; ++dg) {
            float4 wv = *(const float4*)&wlt[c][dg * 4];
#pragma unroll
            for (int k = 0; k < 16; ++k) {
                float4 xvv = *(const float4*)&x1[w][k][dg * 4];
                scv[k] += xvv.x * wv.x + xvv.y * wv.y + xvv.z * wv.z + xvv.w * wv.w;
            }
        }
        float m = scv[0];
#pragma unroll
        for (int k = 1; k < 16; ++k) m = fmaxf(m, scv[k]);
        float sum = 0.f, p1 = 0.f;
#pragma unroll
        for (int k = 0; k < 16; ++k) { float e = __expf(scv[k] - m); sum += e; p1 += e * col[k]; }
        p1 /= sum;
        p1b[w][c] = p1;

        if (c < OUTC) {
            float acc = bmlp[c];
#pragma unroll
            for (int d = 0; d < 64; ++d) acc += p1b[w][d] * wm[d][c];
            preout[(size_t)p * OUTC + c] = acc;
            s += acc; s2 += (double)acc * acc;
        }
    }
    if (c < OUTC) { red[w][c][0] = s; red[w][c][1] = s2; }
    __syncthreads();
    if (t < OUTC) {
        double ts = red[0][t][0], ts2 = red[0][t][1];
        for (int g = 1; g < 4; ++g) { ts += red[g][t][0]; ts2 += red[g][t][1]; }
        atomicAdd(&stats[stat_base + t], ts);
        atomicAdd(&stats[stat_base + OUTC + t], ts2);
    }
}

// ---------------- K9: final mlp2 + shortcut BN + residual leaky + transposed write ----
__global__ __launch_bounds__(256) void k_out(const float* __restrict__ pre2,
                                             const float* __restrict__ short_pre,
                                             const float* __restrict__ W2, const float* __restrict__ b2,
                                             const double* __restrict__ stats,
                                             const float* __restrict__ g_a2, const float* __restrict__ be_a2,
                                             const float* __restrict__ g_s, const float* __restrict__ be_s,
                                             float* __restrict__ out) {
    __shared__ __align__(16) float w2[64][128];
    __shared__ float sc2[64], sh2[64], scs[128], shs[128], bb[128];
    int t = threadIdx.x;
    int pl = t & 63, seg = t >> 6;
    for (int e = t; e < 8192; e += 256) w2[e >> 7][e & 127] = W2[e];
    if (t < 64) { float2 p = fin_pair(stats, S_ATT2, t, 64, (double)BNTOT, g_a2, be_a2); sc2[t] = p.x; sh2[t] = p.y; }
    if (t >= 64 && t < 192) { int ch = t - 64; float2 p = fin_pair(stats, S_SHORT, ch, 128, (double)BNTOT, g_s, be_s); scs[ch] = p.x; shs[ch] = p.y; }
    if (t < 128) bb[t] = b2[t];
    __syncthreads();

    int p = blockIdx.x * 64 + pl;
    int b = p >> 13, n = p & 8191;
    const float* pr = pre2 + (size_t)p * 64;
    float xa[64];
#pragma unroll
    for (int c = 0; c < 64; c += 4) {
        float4 v = *(const float4*)&pr[c];
        xa[c + 0] = fmaxf(v.x * sc2[c + 0] + sh2[c + 0], 0.f);
        xa[c + 1] = fmaxf(v.y * sc2[c + 1] + sh2[c + 1], 0.f);
        xa[c + 2] = fmaxf(v.z * sc2[c + 2] + sh2[c + 2], 0.f);
        xa[c + 3] = fmaxf(v.w * sc2[c + 3] + sh2[c + 3], 0.f);
    }
    const float* shp = short_pre + (size_t)p * 128;
    int obase = seg * 32;
    for (int o = obase; o < obase + 32; o += 4) {
        float a0 = bb[o], a1 = bb[o + 1], a2 = bb[o + 2], a3 = bb[o + 3];
#pragma unroll
        for (int cc = 0; cc < 64; ++cc) {
            float4 wv = *(const float4*)&w2[cc][o];
            float x = xa[cc];
            a0 += x * wv.x; a1 += x * wv.y; a2 += x * wv.z; a3 += x * wv.w;
        }
        float4 sv = *(const float4*)&shp[o];
        float r0 = a0 + (sv.x * scs[o] + shs[o]);
        float r1 = a1 + (sv.y * scs[o + 1] + shs[o + 1]);
        float r2 = a2 + (sv.z * scs[o + 2] + shs[o + 2]);
        float r3 = a3 + (sv.w * scs[o + 3] + shs[o + 3]);
        out[((size_t)(b * C2 + o + 0)) * NN + n] = r0 >= 0.f ? r0 : 0.01f * r0;
        out[((size_t)(b * C2 + o + 1)) * NN + n] = r1 >= 0.f ? r1 : 0.01f * r1;
        out[((size_t)(b * C2 + o + 2)) * NN + n] = r2 >= 0.f ? r2 : 0.01f * r2;
        out[((size_t)(b * C2 + o + 3)) * NN + n] = r3 >= 0.f ? r3 : 0.01f * r3;
    }
}

extern "C" void kernel_launch(void* const* d_in, const int* in_sizes, int n_in,
                              void* d_out, int out_size, void* d_ws, size_t ws_size,
                              hipStream_t stream) {
    const float* coords    = (const float*)d_in[0];
    const float* features  = (const float*)d_in[1];
    const float* W_mlp1    = (const float*)d_in[2];
    const float* b_mlp1    = (const float*)d_in[3];
    const float* W_lse1    = (const float*)d_in[4];
    const float* b_lse1    = (const float*)d_in[5];
    const float* g_lse1    = (const float*)d_in[6];
    const float* be_lse1   = (const float*)d_in[7];
    const float* W_att1_lin= (const float*)d_in[8];
    const float* W_att1_mlp= (const float*)d_in[9];
    const float* b_att1_mlp= (const float*)d_in[10];
    const float* g_att1    = (const float*)d_in[11];
    const float* be_att1   = (const float*)d_in[12];
    const float* W_lse2    = (const float*)d_in[13];
    const float* b_lse2    = (const float*)d_in[14];
    const float* g_lse2    = (const float*)d_in[15];
    const float* be_lse2   = (const float*)d_in[16];
    const float* W_att2_lin= (const float*)d_in[17];
    const float* W_att2_mlp= (const float*)d_in[18];
    const float* b_att2_mlp= (const float*)d_in[19];
    const float* g_att2    = (const float*)d_in[20];
    const float* be_att2   = (const float*)d_in[21];
    const float* W_mlp2    = (const float*)d_in[22];
    const float* b_mlp2    = (const float*)d_in[23];
    const float* W_short   = (const float*)d_in[24];
    const float* b_short   = (const float*)d_in[25];
    const float* g_short   = (const float*)d_in[26];
    const float* be_short  = (const float*)d_in[27];

    float* ws = (float*)d_ws;
    float4* cp4      = (float4*)(ws + OFF_CP4);
    float* se        = ws + OFF_SE;
    float* xf        = ws + OFF_XF;
    float* short_pre = ws + OFF_SHORT;
    float* pre1      = ws + OFF_PRE1;
    float* pre2      = ws + OFF_PRE2;
    double* stats    = (double*)(ws + OFF_STATS);
    int* counts      = (int*)(ws + OFF_COUNTS);
    int* code        = (int*)(ws + OFF_CODE);
    float4* cps      = (float4*)(ws + OFF_CPS);
    int* oidxArr     = (int*)(ws + OFF_OIDX);
    float* bboxg     = ws + OFF_BBOX;
    float* out       = (float*)d_out;

    hipMemsetAsync(stats, 0, S_TOTAL * 8 + 2 * NCELL * 4, stream);

    k_prep<<<BNTOT / 256, 256, 0, stream>>>(coords, cp4, code, counts);
    k_scan<<<1, 256, 0, stream>>>(counts);
    k_scatter<<<BNTOT / 256, 256, 0, stream>>>(cp4, code, counts, cps, oidxArr);
    k_bbox<<<BB * NCHUNK, 64, 0, stream>>>(cps, bboxg);
    k_knn<<<512, 256, 0, stream>>>(cps, oidxArr, cp4, bboxg, se);
    k_feat<<<512, 128, 0, stream>>>(features, W_mlp1, b_mlp1, W_short, b_short,
                                    xf, short_pre, stats);
    k_lse_stats<<<512, 256, 0, stream>>>(se, W_lse1, b_lse1, W_lse2, b_lse2, stats);
    k_att<32, false><<<512, 256, 0, stream>>>(se, xf, W_lse1, b_lse1, W_att1_lin,
                                              W_att1_mlp, b_att1_mlp, stats,
                                              S_LSE1, 0, S_ATT1,
                                              g_lse1, be_lse1, nullptr, nullptr, pre1);
    k_att<64, true><<<512, 256, 0, stream>>>(se, pre1, W_lse2, b_lse2, W_att2_lin,
                                             W_att2_mlp, b_att2_mlp, stats,
                                             S_LSE2, S_ATT1, S_ATT2,
                                             g_lse2, be_lse2, g_att1, be_att1, pre2);
    k_out<<<BNTOT / 64, 256, 0, stream>>>(pre2, short_pre, W_mlp2, b_mlp2, stats,
                                          g_att2, be_att2, g_short, be_short, out);
}

// Round 9
// 403.300 us; speedup vs baseline: 2.0058x; 1.6798x over previous
//
#include <hip/hip_runtime.h>
#include <cfloat>
#include <cmath>

#define DEV __device__ __forceinline__

constexpr int BB = 2, NN = 8192, KK = 16, CIN = 32, HH = 32, CO = 64, C2 = 128;
constexpr int BNTOT = BB * NN;        // 16384
constexpr int BNKROWS = BB * NN * KK; // 262144
constexpr float EPSF = 1e-6f;

// stats indices (doubles): [sum.., sumsq..] per group
constexpr int S_LSE1 = 0, S_LSE2 = 64, S_ATT1 = 128, S_ATT2 = 192, S_SHORT = 320, S_TOTAL = 576;

// workspace layout (in floats)
constexpr size_t OFF_CP4   = 0;                                  // (x,y,z,sq): 16384*4
constexpr size_t OFF_SE    = OFF_CP4 + (size_t)BNTOT * 4;        // se (B,N,K,10)
constexpr size_t OFF_XF    = OFF_SE + (size_t)BNKROWS * 10;      // mlp1 out (B,N,32)
constexpr size_t OFF_SHORT = OFF_XF + (size_t)BNTOT * HH;        // shortcut pre-BN (B,N,128)
constexpr size_t OFF_PRE1  = OFF_SHORT + (size_t)BNTOT * C2;     // att1 pre-BN (B,N,32)
constexpr size_t OFF_PRE2  = OFF_PRE1 + (size_t)BNTOT * HH;      // att2 pre-BN (B,N,64)
constexpr size_t OFF_STATS = OFF_PRE2 + (size_t)BNTOT * CO;      // doubles x576 (even offset -> 8B aligned)

// ---------------- K0: pack (x,y,z,sq) ----------------
__global__ __launch_bounds__(256) void k_prep(const float* __restrict__ coords,
                                              float4* __restrict__ cp4) {
#pragma clang fp contract(off)
    int i = blockIdx.x * 256 + threadIdx.x;
    if (i >= BNTOT) return;
    float x = coords[3 * i], y = coords[3 * i + 1], z = coords[3 * i + 2];
    float sq = (x * x + y * y) + z * z;   // match numpy sum order, no FMA
    cp4[i] = make_float4(x, y, z, sq);
}

DEV float dist2(float4 qc, float4 c) {
#pragma clang fp contract(off)
    float dot = (qc.x * c.x + qc.y * c.y) + qc.z * c.z;
    return (qc.w + c.w) - 2.0f * dot;   // exact jax/np expansion formula
}

// order-preserving float->uint encoding (monotone for all finite floats)
DEV unsigned encf(float f) {
    unsigned u = __float_as_uint(f);
    return (u & 0x80000000u) ? ~u : (u | 0x80000000u);
}
DEV float decf(unsigned e) {
    unsigned u = (e & 0x80000000u) ? (e & 0x7FFFFFFFu) : ~e;
    return __uint_as_float(u);
}

// strict-< sorted insert (stable == lex for ascending-index insertion order)
DEV void ins16(float (&dl)[16], int (&il)[16], float d, int id) {
    float dk = d; int jk = id;
#pragma unroll
    for (int r = 0; r < 16; ++r) {
        bool c = dk < dl[r];
        float td = dl[r]; int ti = il[r];
        dl[r] = c ? dk : dl[r]; il[r] = c ? jk : il[r];
        dk = c ? td : dk; jk = c ? ti : jk;
    }
}

// lexicographic (d, idx) insert — for merging lists from different index ranges
DEV void ins16_lex(float (&dl)[16], int (&il)[16], float d, int id) {
    float dk = d; int jk = id;
#pragma unroll
    for (int r = 0; r < 16; ++r) {
        bool c = (dk < dl[r]) || (dk == dl[r] && jk < il[r]);
        float td = dl[r]; int ti = il[r];
        dl[r] = c ? dk : dl[r]; il[r] = c ? jk : il[r];
        dk = c ? td : dk; jk = c ? ti : jk;
    }
}

// ---------------- K1: flat-scan KNN + spatial encoding (R3 structure) ----------------
// grid 512 = 2 batches x 256 query-groups of 32; block 256; thread: query=t&31,
// partition=t>>5 (8 x 1024 candidates). Candidates from L2 (cp4 = 128KB/batch;
// 32 lanes/partition share each address -> broadcast). Shared per-query union
// threshold (LDS atomicMin over ordered-uint; stale reads are larger -> safe).
// Buffered inserts amortize the wave-divergent sorted-insert chain.
// NOTE: regular dense scan deliberately chosen over bbox pruning — R4/R5/R8
// showed pruning's schedule costs (imbalance/barriers/stragglers) exceed the
// arithmetic it saves at N=8192.
__global__ __launch_bounds__(256) void k_knn(const float4* __restrict__ cp4,
                                             float* __restrict__ se) {
    __shared__ float mdl[8][32][17];       // published lists (pad 17 vs bank conflicts)
    __shared__ int   mil[8][32][17];
    __shared__ unsigned thr[32];           // per-query union threshold (encoded)
    uint2 (*buf)[256] = reinterpret_cast<uint2(*)[256]>(&mdl[0][0][0]);  // overlay: 14336B < 17408B; dead before mdl first written

    int t = threadIdx.x;
    int b = blockIdx.x >> 8;
    int qbase = (blockIdx.x & 255) * 32;
    int ql = t & 31, part = t >> 5;
    const float4* cp = cp4 + (size_t)b * NN;
    float4 qc = cp[qbase + ql];

    if (t < 32) thr[t] = encf(FLT_MAX);
    __syncthreads();

    float dl[16]; int il[16];
#pragma unroll
    for (int i = 0; i < 16; ++i) { dl[i] = FLT_MAX; il[i] = 0; }

    int cb = part * 1024;
    // seed: first 16 candidates of the partition (unconditional inserts)
#pragma unroll
    for (int k = 0; k < 16; ++k) ins16(dl, il, dist2(qc, cp[cb + k]), cb + k);
    atomicMin(&thr[ql], encf(dl[15]));
    float Tf = dl[15];
    int cnt = 0;

    // prefetch pipeline: candidates one iteration ahead; threshold one iter stale
    float4 n0 = cp[cb + 16], n1 = cp[cb + 17], n2 = cp[cb + 18], n3 = cp[cb + 19];
    unsigned te = thr[ql];
    for (int j = cb + 16; j < cb + 1024; j += 4) {
        float4 c0 = n0, c1 = n1, c2 = n2, c3 = n3;
        n0 = cp[j + 4]; n1 = cp[j + 5]; n2 = cp[j + 6]; n3 = cp[j + 7]; // 64B tail over-read lands in ws (se region), values unused
        float d0 = dist2(qc, c0), d1 = dist2(qc, c1), d2v = dist2(qc, c2), d3 = dist2(qc, c3);
        bool p0 = d0 <= Tf, p1 = d1 <= Tf, p2 = d2v <= Tf, p3 = d3 <= Tf;
        if (__any(p0 | p1 | p2 | p3)) {
            if (p0) { buf[cnt][t] = make_uint2(__float_as_uint(d0), (unsigned)(j)); ++cnt; }
            if (p1) { buf[cnt][t] = make_uint2(__float_as_uint(d1), (unsigned)(j + 1)); ++cnt; }
            if (p2) { buf[cnt][t] = make_uint2(__float_as_uint(d2v), (unsigned)(j + 2)); ++cnt; }
            if (p3) { buf[cnt][t] = make_uint2(__float_as_uint(d3), (unsigned)(j + 3)); ++cnt; }
            if (__any(cnt >= 4)) {
#pragma unroll
                for (int s = 0; s < 7; ++s) {
                    if (s < cnt) {
                        uint2 v = buf[s][t];
                        float d = __uint_as_float(v.x);
                        if (d < dl[15]) ins16(dl, il, d, (int)v.y);
                    }
                }
                cnt = 0;
                atomicMin(&thr[ql], encf(dl[15]));
            }
        }
        Tf = decf(te);        // adopt last iteration's published min
        te = thr[ql];         // issue refresh for next iteration (latency hidden)
    }
    if (__any(cnt > 0)) {     // final flush
#pragma unroll
        for (int s = 0; s < 7; ++s) {
            if (s < cnt) {
                uint2 v = buf[s][t];
                float d = __uint_as_float(v.x);
                if (d < dl[15]) ins16(dl, il, d, (int)v.y);
            }
        }
    }

    __syncthreads();   // protect buf -> mdl overlay (all waves done with buf)
#pragma unroll
    for (int i = 0; i < 16; ++i) { mdl[part][ql][i] = dl[i]; mil[part][ql][i] = il[i]; }
    __syncthreads();

    // pairwise merge tree 8->4->2->1 (lex compare for cross-partition stability)
    for (int half = 4; half >= 1; half >>= 1) {
        if (part < half) {
#pragma unroll
            for (int i = 0; i < 16; ++i) {
                float d = mdl[part + half][ql][i]; int id = mil[part + half][ql][i];
                if (d < dl[15] || (d == dl[15] && id < il[15])) ins16_lex(dl, il, d, id);
            }
#pragma unroll
            for (int i = 0; i < 16; ++i) { mdl[part][ql][i] = dl[i]; mil[part][ql][i] = il[i]; }
        }
        __syncthreads();
    }

    // epilogue: all 256 threads write se rows (2 (q,k) slots each)
    for (int s = t; s < 512; s += 256) {
        int qq = s >> 4, k = s & 15;
        float d2s = mdl[0][qq][k]; int id = mil[0][qq][k];
        float4 qc2 = cp[qbase + qq];
        float4 nb = cp[id];
        float dist = sqrtf(fmaxf(d2s, 1e-12f));
        float* sp = se + ((size_t)(b * NN + qbase + qq) * KK + k) * 10;
        sp[0] = qc2.x; sp[1] = qc2.y; sp[2] = qc2.z;
        sp[3] = nb.x;  sp[4] = nb.y;  sp[5] = nb.z;
        sp[6] = qc2.x - nb.x; sp[7] = qc2.y - nb.y; sp[8] = qc2.z - nb.z;
        sp[9] = dist;
    }
}

// ---------------- K2: mlp1 + shortcut linear + shortcut BN stats ----------------
__global__ __launch_bounds__(128) void k_feat(const float* __restrict__ feat,
                                              const float* __restrict__ Wm1, const float* __restrict__ bm1,
                                              const float* __restrict__ Wsh, const float* __restrict__ bsh,
                                              float* __restrict__ xf, float* __restrict__ short_pre,
                                              double* __restrict__ stats) {
    __shared__ float fl[32][33];
    int t = threadIdx.x;
    int pbase = blockIdx.x * 32;
    float wcol[32];
#pragma unroll
    for (int i = 0; i < 32; ++i) wcol[i] = Wsh[i * C2 + t];
    float wm[32];
    if (t < 32) {
#pragma unroll
        for (int i = 0; i < 32; ++i) wm[i] = Wm1[i * HH + t];
    }
    float bs = bsh[t];
    float bm = (t < 32) ? bm1[t] : 0.f;
    double s = 0.0, s2 = 0.0;

    for (int e = t; e < 1024; e += 128) {
        int p = e >> 5, i = e & 31;
        fl[p][i] = feat[(size_t)(pbase + p) * CIN + i];
    }
    __syncthreads();
    for (int p = 0; p < 32; ++p) {
        float acc = bs;
#pragma unroll
        for (int i = 0; i < 32; ++i) acc += fl[p][i] * wcol[i];
        int gp = pbase + p;
        short_pre[(size_t)gp * C2 + t] = acc;
        s += acc; s2 += (double)acc * acc;
        if (t < 32) {
            float xv = bm;
#pragma unroll
            for (int i = 0; i < 32; ++i) xv += fl[p][i] * wm[i];
            xf[(size_t)gp * HH + t] = xv >= 0.f ? xv : 0.2f * xv;
        }
    }
    atomicAdd(&stats[S_SHORT + t], s);
    atomicAdd(&stats[S_SHORT + C2 + t], s2);
}

// ---------------- K3: lse1+lse2 linear BN stats (LDS-staged) ----------------
__global__ __launch_bounds__(256) void k_lse_stats(const float* __restrict__ se,
                                                   const float* __restrict__ W1, const float* __restrict__ b1,
                                                   const float* __restrict__ W2, const float* __restrict__ b2,
                                                   double* __restrict__ stats) {
    __shared__ float srows[256][10];
    __shared__ double red[4][64][2];
    int t = threadIdx.x;
    int c = t & 63, grp = t >> 6;
    int ch = c & 31; bool second = c >= 32;
    const float* W = second ? W2 : W1;
    float wcol[10];
#pragma unroll
    for (int d = 0; d < 10; ++d) wcol[d] = W[d * HH + ch];
    float bb = second ? b2[ch] : b1[ch];
    double s = 0.0, s2 = 0.0;
    int rbase = blockIdx.x * 512;

    for (int tile = 0; tile < 2; ++tile) {
        __syncthreads();
        const float* src = se + (size_t)(rbase + tile * 256) * 10;
        for (int e = t; e < 2560; e += 256) srows[e / 10][e % 10] = src[e];
        __syncthreads();
        int r0 = grp * 64;
        for (int r = r0; r < r0 + 64; ++r) {
            float acc = bb;
#pragma unroll
            for (int d = 0; d < 10; ++d) acc += srows[r][d] * wcol[d];
            s += acc; s2 += (double)acc * acc;
        }
    }
    red[grp][c][0] = s; red[grp][c][1] = s2;
    __syncthreads();
    if (grp == 0) {
        for (int g = 1; g < 4; ++g) { s += red[g][c][0]; s2 += red[g][c][1]; }
        int base = second ? S_LSE2 : S_LSE1;
        atomicAdd(&stats[base + ch], s);
        atomicAdd(&stats[base + 32 + ch], s2);
    }
}

// BN scale/shift from raw stats (computed redundantly in consumer prologues)
DEV float2 fin_pair(const double* stats, int sbase, int ch, int nch, double M,
                    const float* g, const float* be) {
    double mean = stats[sbase + ch] / M;
    double var = stats[sbase + nch + ch] / M - mean * mean;
    double scd = (double)g[ch] / sqrt(var + (double)EPSF);
    return make_float2((float)scd, (float)((double)be[ch] - mean * scd));
}

// ---------------- K5/K7: fused LocSE + attentive pooling + MLP ----------------
template <int OUTC, bool SECOND>
__global__ __launch_bounds__(256) void k_att(const float* __restrict__ se,
                                             const float* __restrict__ featsrc,
                                             const float* __restrict__ Wlse, const float* __restrict__ blse,
                                             const float* __restrict__ Wlin,
                                             const float* __restrict__ Wmlp, const float* __restrict__ bmlp,
                                             double* __restrict__ stats, int lse_sbase, int feat_sbase, int stat_base,
                                             const float* __restrict__ g_lse, const float* __restrict__ be_lse,
                                             const float* __restrict__ g_f, const float* __restrict__ be_f,
                                             float* __restrict__ preout) {
    __shared__ __align__(16) float wlt[64][68];
    __shared__ float wm[64][OUTC];
    __shared__ __align__(16) float x1[4][16][40];
    __shared__ float fv[4][32];
    __shared__ float p1b[4][64];
    __shared__ double red[4][OUTC][2];

    int t = threadIdx.x, w = t >> 6, c = t & 63;
    int ch = c & 31, half = c >> 5;
    for (int e = t; e < 4096; e += 256) wlt[e & 63][e >> 6] = Wlin[e];
    for (int e = t; e < 64 * OUTC; e += 256) wm[e / OUTC][e % OUTC] = Wmlp[e];

    float wf[10]; float bf;
    {
        float2 p = fin_pair(stats, lse_sbase, ch, 32, (double)BNKROWS, g_lse, be_lse);
#pragma unroll
        for (int d = 0; d < 10; ++d) wf[d] = Wlse[d * 32 + ch] * p.x;
        bf = blse[ch] * p.x + p.y;
    }
    float fa = 1.f, fb = 0.f;
    if (SECOND && c >= 32) {
        float2 p = fin_pair(stats, feat_sbase, ch, 32, (double)BNTOT, g_f, be_f);
        fa = p.x; fb = p.y;
    }
    double s = 0.0, s2 = 0.0;
    __syncthreads();

    for (int i = 0; i < 8; ++i) {
        int p = blockIdx.x * 32 + w * 8 + i;

        int kbase = half * 8;
        const float* sp = se + (size_t)p * (KK * 10) + kbase * 10;
        float myv[8];
#pragma unroll
        for (int kk = 0; kk < 8; ++kk) {
            float acc = bf;
#pragma unroll
            for (int d = 0; d < 10; ++d) acc += sp[kk * 10 + d] * wf[d];
            myv[kk] = fmaxf(acc, 0.f);
        }
#pragma unroll
        for (int kk = 0; kk < 8; ++kk) x1[w][kbase + kk][ch] = myv[kk];

        float xv = 0.f;
        if (c >= 32) {
            xv = featsrc[(size_t)p * 32 + ch];
            if (SECOND) xv = fmaxf(xv * fa + fb, 0.f);
            fv[w][ch] = xv;
        }

        float col[16];
        if (c < 32) {
#pragma unroll
            for (int kk = 0; kk < 8; ++kk) col[kk] = myv[kk];
#pragma unroll
            for (int kk = 0; kk < 8; ++kk) col[8 + kk] = x1[w][8 + kk][ch];
        } else {
#pragma unroll
            for (int k = 0; k < 16; ++k) col[k] = xv;
        }

        float cst = 0.f;
#pragma unroll
        for (int dg = 8; dg < 16; ++dg) {
            float4 wv = *(const float4*)&wlt[c][dg * 4];
            float4 xvv = *(const float4*)&fv[w][(dg - 8) * 4];
            cst += xvv.x * wv.x + xvv.y * wv.y + xvv.z * wv.z + xvv.w * wv.w;
        }
        float scv[16];
#pragma unroll
        for (int k = 0; k < 16; ++k) scv[k] = cst;
        for (int dg = 0; dg < 8; ++dg) {
            float4 wv = *(const float4*)&wlt[c][dg * 4];
#pragma unroll
            for (int k = 0; k < 16; ++k) {
                float4 xvv = *(const float4*)&x1[w][k][dg * 4];
                scv[k] += xvv.x * wv.x + xvv.y * wv.y + xvv.z * wv.z + xvv.w * wv.w;
            }
        }
        float m = scv[0];
#pragma unroll
        for (int k = 1; k < 16; ++k) m = fmaxf(m, scv[k]);
        float sum = 0.f, p1 = 0.f;
#pragma unroll
        for (int k = 0; k < 16; ++k) { float e = __expf(scv[k] - m); sum += e; p1 += e * col[k]; }
        p1 /= sum;
        p1b[w][c] = p1;

        if (c < OUTC) {
            float acc = bmlp[c];
#pragma unroll
            for (int d = 0; d < 64; ++d) acc += p1b[w][d] * wm[d][c];
            preout[(size_t)p * OUTC + c] = acc;
            s += acc; s2 += (double)acc * acc;
        }
    }
    if (c < OUTC) { red[w][c][0] = s; red[w][c][1] = s2; }
    __syncthreads();
    if (t < OUTC) {
        double ts = red[0][t][0], ts2 = red[0][t][1];
        for (int g = 1; g < 4; ++g) { ts += red[g][t][0]; ts2 += red[g][t][1]; }
        atomicAdd(&stats[stat_base + t], ts);
        atomicAdd(&stats[stat_base + OUTC + t], ts2);
    }
}

// ---------------- K9: final mlp2 + shortcut BN + residual leaky + transposed write ----
__global__ __launch_bounds__(256) void k_out(const float* __restrict__ pre2,
                                             const float* __restrict__ short_pre,
                                             const float* __restrict__ W2, const float* __restrict__ b2,
                                             const double* __restrict__ stats,
                                             const float* __restrict__ g_a2, const float* __restrict__ be_a2,
                                             const float* __restrict__ g_s, const float* __restrict__ be_s,
                                             float* __restrict__ out) {
    __shared__ __align__(16) float w2[64][128];
    __shared__ float sc2[64], sh2[64], scs[128], shs[128], bb[128];
    int t = threadIdx.x;
    int pl = t & 63, seg = t >> 6;
    for (int e = t; e < 8192; e += 256) w2[e >> 7][e & 127] = W2[e];
    if (t < 64) { float2 p = fin_pair(stats, S_ATT2, t, 64, (double)BNTOT, g_a2, be_a2); sc2[t] = p.x; sh2[t] = p.y; }
    if (t >= 64 && t < 192) { int ch = t - 64; float2 p = fin_pair(stats, S_SHORT, ch, 128, (double)BNTOT, g_s, be_s); scs[ch] = p.x; shs[ch] = p.y; }
    if (t < 128) bb[t] = b2[t];
    __syncthreads();

    int p = blockIdx.x * 64 + pl;
    int b = p >> 13, n = p & 8191;
    const float* pr = pre2 + (size_t)p * 64;
    float xa[64];
#pragma unroll
    for (int c = 0; c < 64; c += 4) {
        float4 v = *(const float4*)&pr[c];
        xa[c + 0] = fmaxf(v.x * sc2[c + 0] + sh2[c + 0], 0.f);
        xa[c + 1] = fmaxf(v.y * sc2[c + 1] + sh2[c + 1], 0.f);
        xa[c + 2] = fmaxf(v.z * sc2[c + 2] + sh2[c + 2], 0.f);
        xa[c + 3] = fmaxf(v.w * sc2[c + 3] + sh2[c + 3], 0.f);
    }
    const float* shp = short_pre + (size_t)p * 128;
    int obase = seg * 32;
    for (int o = obase; o < obase + 32; o += 4) {
        float a0 = bb[o], a1 = bb[o + 1], a2 = bb[o + 2], a3 = bb[o + 3];
#pragma unroll
        for (int cc = 0; cc < 64; ++cc) {
            float4 wv = *(const float4*)&w2[cc][o];
            float x = xa[cc];
            a0 += x * wv.x; a1 += x * wv.y; a2 += x * wv.z; a3 += x * wv.w;
        }
        float4 sv = *(const float4*)&shp[o];
        float r0 = a0 + (sv.x * scs[o] + shs[o]);
        float r1 = a1 + (sv.y * scs[o + 1] + shs[o + 1]);
        float r2 = a2 + (sv.z * scs[o + 2] + shs[o + 2]);
        float r3 = a3 + (sv.w * scs[o + 3] + shs[o + 3]);
        out[((size_t)(b * C2 + o + 0)) * NN + n] = r0 >= 0.f ? r0 : 0.01f * r0;
        out[((size_t)(b * C2 + o + 1)) * NN + n] = r1 >= 0.f ? r1 : 0.01f * r1;
        out[((size_t)(b * C2 + o + 2)) * NN + n] = r2 >= 0.f ? r2 : 0.01f * r2;
        out[((size_t)(b * C2 + o + 3)) * NN + n] = r3 >= 0.f ? r3 : 0.01f * r3;
    }
}

extern "C" void kernel_launch(void* const* d_in, const int* in_sizes, int n_in,
                              void* d_out, int out_size, void* d_ws, size_t ws_size,
                              hipStream_t stream) {
    const float* coords    = (const float*)d_in[0];
    const float* features  = (const float*)d_in[1];
    const float* W_mlp1    = (const float*)d_in[2];
    const float* b_mlp1    = (const float*)d_in[3];
    const float* W_lse1    = (const float*)d_in[4];
    const float* b_lse1    = (const float*)d_in[5];
    const float* g_lse1    = (const float*)d_in[6];
    const float* be_lse1   = (const float*)d_in[7];
    const float* W_att1_lin= (const float*)d_in[8];
    const float* W_att1_mlp= (const float*)d_in[9];
    const float* b_att1_mlp= (const float*)d_in[10];
    const float* g_att1    = (const float*)d_in[11];
    const float* be_att1   = (const float*)d_in[12];
    const float* W_lse2    = (const float*)d_in[13];
    const float* b_lse2    = (const float*)d_in[14];
    const float* g_lse2    = (const float*)d_in[15];
    const float* be_lse2   = (const float*)d_in[16];
    const float* W_att2_lin= (const float*)d_in[17];
    const float* W_att2_mlp= (const float*)d_in[18];
    const float* b_att2_mlp= (const float*)d_in[19];
    const float* g_att2    = (const float*)d_in[20];
    const float* be_att2   = (const float*)d_in[21];
    const float* W_mlp2    = (const float*)d_in[22];
    const float* b_mlp2    = (const float*)d_in[23];
    const float* W_short   = (const float*)d_in[24];
    const float* b_short   = (const float*)d_in[25];
    const float* g_short   = (const float*)d_in[26];
    const float* be_short  = (const float*)d_in[27];

    float* ws = (float*)d_ws;
    float4* cp4      = (float4*)(ws + OFF_CP4);
    float* se        = ws + OFF_SE;
    float* xf        = ws + OFF_XF;
    float* short_pre = ws + OFF_SHORT;
    float* pre1      = ws + OFF_PRE1;
    float* pre2      = ws + OFF_PRE2;
    double* stats    = (double*)(ws + OFF_STATS);
    float* out       = (float*)d_out;

    hipMemsetAsync(stats, 0, S_TOTAL * sizeof(double), stream);

    k_prep<<<BNTOT / 256, 256, 0, stream>>>(coords, cp4);
    k_knn<<<512, 256, 0, stream>>>(cp4, se);
    k_feat<<<512, 128, 0, stream>>>(features, W_mlp1, b_mlp1, W_short, b_short,
                                    xf, short_pre, stats);
    k_lse_stats<<<512, 256, 0, stream>>>(se, W_lse1, b_lse1, W_lse2, b_lse2, stats);
    k_att<32, false><<<512, 256, 0, stream>>>(se, xf, W_lse1, b_lse1, W_att1_lin,
                                              W_att1_mlp, b_att1_mlp, stats,
                                              S_LSE1, 0, S_ATT1,
                                              g_lse1, be_lse1, nullptr, nullptr, pre1);
    k_att<64, true><<<512, 256, 0, stream>>>(se, pre1, W_lse2, b_lse2, W_att2_lin,
                                             W_att2_mlp, b_att2_mlp, stats,
                                             S_LSE2, S_ATT1, S_ATT2,
                                             g_lse2, be_lse2, g_att1, be_att1, pre2);
    k_out<<<BNTOT / 64, 256, 0, stream>>>(pre2, short_pre, W_mlp2, b_mlp2, stats,
                                          g_att2, be_att2, g_short, be_short, out);
}